// Round 5
// baseline (548.340 us; speedup 1.0000x reference)
//
#include <hip/hip_runtime.h>

// GraphSAGE 3-layer encoder.
// Per layer: CSR build (hist -> scan -> fill) -> gather-mean (writes mean as
// interleaved split-bf16 rows) -> MFMA compute (32 rows/wave, LDS-staged
// weights shared by the block, split-bf16 3-term products):
// out = mean@Wl + b + x@Wr, PReLU.

constexpr int cN0 = 400000, cN1 = 200000, cN2 = 100000, cN3 = 50000;
constexpr int cE1 = 500000, cE2 = 300000, cE3 = 150000;

#define NDIV_UP(a, b) (((a) + (b) - 1) / (b))

typedef __attribute__((ext_vector_type(8))) short bf16x8;
typedef __attribute__((ext_vector_type(4))) float f32x4;
typedef __attribute__((ext_vector_type(4))) unsigned u32x4;

__device__ __forceinline__ unsigned fbits(float f) {
  return __builtin_bit_cast(unsigned, f);
}
__device__ __forceinline__ float ffrom(unsigned u) {
  return __builtin_bit_cast(float, u);
}
__device__ __forceinline__ unsigned short f2bf(float f) {  // round-to-nearest
  unsigned u = fbits(f);
  unsigned r = u + 0x7FFFu + ((u >> 16) & 1u);
  return (unsigned short)(r >> 16);
}
__device__ __forceinline__ float bf2f(unsigned short h) {
  return ffrom((unsigned)h << 16);
}

// Detect whether index buffers are int64 (JAX x64) or int32.
__global__ void detect_idx64_kernel(const void* __restrict__ src, int E,
                                    long long nmax, int* __restrict__ flag) {
  if (threadIdx.x == 0 && blockIdx.x == 0) {
    const long long* p = (const long long*)src;
    int n = E < 512 ? E : 512;
    int ok = 1;
    for (int i = 0; i < n; ++i) {
      long long v = p[i];
      if (v < 0 || v >= nmax) { ok = 0; break; }
    }
    *flag = ok;
  }
}

__device__ __forceinline__ int load_idx(const void* p, int i, int flag) {
  return flag ? (int)((const long long*)p)[i] : ((const int*)p)[i];
}

__global__ void hist_kernel(const void* __restrict__ dstv,
                            const int* __restrict__ flag,
                            int* __restrict__ cnt, int E) {
  int e = blockIdx.x * 256 + threadIdx.x;
  if (e >= E) return;
  atomicAdd(&cnt[load_idx(dstv, e, *flag)], 1);
}

// ---- exclusive scan over cnt[n] -> offs[n], 1024 items / block ----
__global__ __launch_bounds__(256) void scan_reduce(const int* __restrict__ cnt,
                                                   int n, int* __restrict__ bsum) {
  __shared__ int s[256];
  int t = threadIdx.x;
  int base = blockIdx.x * 1024 + t * 4;
  int v = 0;
  if (base + 3 < n) {
    int4 c = *(const int4*)(cnt + base);
    v = c.x + c.y + c.z + c.w;
  } else {
    for (int i = 0; i < 4; ++i)
      if (base + i < n) v += cnt[base + i];
  }
  s[t] = v;
  __syncthreads();
  for (int off = 128; off > 0; off >>= 1) {
    if (t < off) s[t] += s[t + off];
    __syncthreads();
  }
  if (t == 0) bsum[blockIdx.x] = s[0];
}

__global__ void scan_bsums(int* __restrict__ bsum, int nb) {
  if (threadIdx.x == 0 && blockIdx.x == 0) {
    int acc = 0;
    for (int i = 0; i < nb; ++i) {
      int t = bsum[i];
      bsum[i] = acc;
      acc += t;
    }
  }
}

__global__ __launch_bounds__(256) void scan_final(const int* __restrict__ cnt,
                                                  int n, const int* __restrict__ bsum,
                                                  int* __restrict__ offs) {
  __shared__ int s[256];
  int t = threadIdx.x;
  int base = blockIdx.x * 1024 + t * 4;
  int v0 = 0, v1 = 0, v2 = 0, v3 = 0;
  if (base + 3 < n) {
    int4 c = *(const int4*)(cnt + base);
    v0 = c.x; v1 = c.y; v2 = c.z; v3 = c.w;
  } else {
    if (base + 0 < n) v0 = cnt[base + 0];
    if (base + 1 < n) v1 = cnt[base + 1];
    if (base + 2 < n) v2 = cnt[base + 2];
  }
  int tsum = v0 + v1 + v2 + v3;
  s[t] = tsum;
  __syncthreads();
  for (int off = 1; off < 256; off <<= 1) {
    int x = (t >= off) ? s[t - off] : 0;
    __syncthreads();
    s[t] += x;
    __syncthreads();
  }
  int excl = s[t] - tsum;
  int o = bsum[blockIdx.x] + excl;
  if (base + 0 < n) offs[base + 0] = o;
  o += v0;
  if (base + 1 < n) offs[base + 1] = o;
  o += v1;
  if (base + 2 < n) offs[base + 2] = o;
  o += v2;
  if (base + 3 < n) offs[base + 3] = o;
}

// Bucket-fill: advances offs[d]; post-fill offs[d] == pre-fill offs[d+1].
__global__ void fill_kernel(const void* __restrict__ srcv,
                            const void* __restrict__ dstv,
                            const int* __restrict__ flag,
                            int* __restrict__ offs, int* __restrict__ eid, int E) {
  int e = blockIdx.x * 256 + threadIdx.x;
  if (e >= E) return;
  int f = *flag;
  int s = load_idx(srcv, e, f);
  int d = load_idx(dstv, e, f);
  int pos = atomicAdd(&offs[d], 1);
  eid[pos] = s;
}

// One wave per destination row; lane owns cols 2l, 2l+1. Writes mean as
// interleaved split-bf16 row: [hi bf16 x128 | lo bf16 x128] (512 B/row).
__global__ __launch_bounds__(256) void gather_mean_kernel(
    const float* __restrict__ hsrc, const int* __restrict__ offs,
    const int* __restrict__ eid, unsigned short* __restrict__ meanR, int n) {
  int row = blockIdx.x * 4 + (threadIdx.x >> 6);
  if (row >= n) return;
  int lane = threadIdx.x & 63;
  int start = row ? offs[row - 1] : 0;
  int end = offs[row];
  float a0 = 0.f, a1 = 0.f, b0 = 0.f, b1 = 0.f;
  int i = start;
  for (; i + 1 < end; i += 2) {
    const float2 v0 = *(const float2*)(hsrc + (size_t)eid[i] * 128 + lane * 2);
    const float2 v1 = *(const float2*)(hsrc + (size_t)eid[i + 1] * 128 + lane * 2);
    a0 += v0.x; a1 += v0.y;
    b0 += v1.x; b1 += v1.y;
  }
  if (i < end) {
    const float2 v0 = *(const float2*)(hsrc + (size_t)eid[i] * 128 + lane * 2);
    a0 += v0.x; a1 += v0.y;
  }
  a0 += b0; a1 += b1;
  float inv = (end > start) ? 1.0f / (float)(end - start) : 0.0f;
  float m0 = a0 * inv, m1 = a1 * inv;
  unsigned u0 = fbits(m0), u1 = fbits(m1);
  unsigned hw = (u0 >> 16) | (u1 & 0xFFFF0000u);  // trunc split, hi
  float r0 = m0 - ffrom(u0 & 0xFFFF0000u);
  float r1 = m1 - ffrom(u1 & 0xFFFF0000u);
  unsigned lw = (fbits(r0) >> 16) | (fbits(r1) & 0xFFFF0000u);
  unsigned short* rp = meanR + (size_t)row * 256;
  *(unsigned*)(rp + lane * 2) = hw;
  *(unsigned*)(rp + 128 + lane * 2) = lw;
}

// Pre-pack weights (all 3 layers) into per-lane MFMA B-fragment order,
// split bf16 hi/lo (round-to-nearest). Per layer: Wlh|Wll|Wrh|Wrl x16384 u16.
// chunk idx = ((ks*8+cf)*64 + l)*8 + j ; k = ks*32+(l>>4)*8+j ; col = cf*16+(l&15).
__global__ void pack_w3_kernel(const float* __restrict__ Wl1, const float* __restrict__ Wr1,
                               const float* __restrict__ Wl2, const float* __restrict__ Wr2,
                               const float* __restrict__ Wl3, const float* __restrict__ Wr3,
                               unsigned short* __restrict__ wpk) {
  int idx = blockIdx.x * 256 + threadIdx.x;
  if (idx >= 3 * 16384) return;
  int L = idx >> 14;
  int r = idx & 16383;
  const float* Wl = L == 0 ? Wl1 : (L == 1 ? Wl2 : Wl3);
  const float* Wr = L == 0 ? Wr1 : (L == 1 ? Wr2 : Wr3);
  unsigned short* o = wpk + L * 65536;
  int j = r & 7, l = (r >> 3) & 63, cf = (r >> 9) & 7, ks = r >> 12;
  int k = ks * 32 + (l >> 4) * 8 + j;
  int col = cf * 16 + (l & 15);
  float vl = Wl[k * 128 + col];
  float vr = Wr[k * 128 + col];
  unsigned short h = f2bf(vl);
  o[r] = h;
  o[16384 + r] = f2bf(vl - bf2f(h));
  h = f2bf(vr);
  o[32768 + r] = h;
  o[49152 + r] = f2bf(vr - bf2f(h));
}

// MFMA compute: 4 waves/block, each wave owns 32 rows (2x 16-row tiles).
// Per ks-step the block stages that ks's 32 KB weight chunk into LDS (4
// contiguous 8 KB regions), so B-fragments come from LDS (conflict-free
// ds_read_b128) and L2 B-traffic is amortized across the block.
// Mean A-frags load directly from interleaved split rows (no conversion);
// x converts fp32->split in-register (truncation). out (fp32) may alias
// meanR: each wave reads only its own 32 rows, all A-reads precede its
// epilogue stores, and waves/blocks own disjoint row ranges.
__global__ __launch_bounds__(256) void compute_mfma3_kernel(
    const unsigned short* __restrict__ meanR, const float* __restrict__ xdst,
    const unsigned short* __restrict__ W,
    const float* __restrict__ bias, const float* __restrict__ alpha,
    float* __restrict__ out, int n) {
  __shared__ __align__(16) unsigned short wlds[16384];  // 32 KB: one ks chunk
  const int tid = threadIdx.x;
  const int lane = tid & 63;
  const int wv = tid >> 6;
  const int rbase = blockIdx.x * 128 + wv * 32;
  const int kb = (lane >> 4) * 8;
  const int arow0 = rbase + (lane & 15);

  f32x4 acc[2][8] = {};

  for (int ks = 0; ks < 4; ++ks) {
    const int k = ks * 32 + kb;
    // Issue A-fragment loads early; latency absorbed by the stage barrier.
    bf16x8 mh[2], ml[2], xh[2], xl[2];
#pragma unroll
    for (int t = 0; t < 2; ++t) {
      const int ar = arow0 + t * 16;
      if (ar < n) {
        const unsigned short* rp = meanR + (size_t)ar * 256 + k;
        mh[t] = *(const bf16x8*)(rp);
        ml[t] = *(const bf16x8*)(rp + 128);
        const float* xp = xdst + (size_t)ar * 128 + k;
        float xv[8];
        *(float4*)&xv[0] = *(const float4*)(xp);
        *(float4*)&xv[4] = *(const float4*)(xp + 4);
        u32x4 hwv, lwv;
#pragma unroll
        for (int p = 0; p < 4; ++p) {
          unsigned ue = fbits(xv[2 * p]), uo = fbits(xv[2 * p + 1]);
          hwv[p] = (ue >> 16) | (uo & 0xFFFF0000u);
          float re = xv[2 * p] - ffrom(ue & 0xFFFF0000u);
          float ro = xv[2 * p + 1] - ffrom(uo & 0xFFFF0000u);
          lwv[p] = (fbits(re) >> 16) | (fbits(ro) & 0xFFFF0000u);
        }
        xh[t] = __builtin_bit_cast(bf16x8, hwv);
        xl[t] = __builtin_bit_cast(bf16x8, lwv);
      } else {
        mh[t] = (bf16x8)0; ml[t] = (bf16x8)0;
        xh[t] = (bf16x8)0; xl[t] = (bf16x8)0;
      }
    }

    // Stage this ks's 32 KB weight chunk into LDS.
    __syncthreads();  // protect wlds from previous iteration's readers
    {
      const unsigned short* src = W + ks * 4096;
#pragma unroll
      for (int i = 0; i < 8; ++i) {
        int idx = tid + i * 256;          // 2048 x 16B chunks
        int arr = idx >> 9, off = idx & 511;
        *(float4*)(wlds + arr * 4096 + off * 8) =
            *(const float4*)(src + (size_t)arr * 16384 + off * 8);
      }
    }
    __syncthreads();

    const unsigned short* wb = wlds + lane * 8;
#pragma unroll
    for (int cf = 0; cf < 8; ++cf) {
      const unsigned short* wp = wb + cf * 512;
      bf16x8 wlh = *(const bf16x8*)(wp);
      bf16x8 wll = *(const bf16x8*)(wp + 4096);
      bf16x8 wrh = *(const bf16x8*)(wp + 8192);
      bf16x8 wrl = *(const bf16x8*)(wp + 12288);
#pragma unroll
      for (int t = 0; t < 2; ++t) {
        acc[t][cf] = __builtin_amdgcn_mfma_f32_16x16x32_bf16(mh[t], wlh, acc[t][cf], 0, 0, 0);
        acc[t][cf] = __builtin_amdgcn_mfma_f32_16x16x32_bf16(ml[t], wlh, acc[t][cf], 0, 0, 0);
        acc[t][cf] = __builtin_amdgcn_mfma_f32_16x16x32_bf16(mh[t], wll, acc[t][cf], 0, 0, 0);
        acc[t][cf] = __builtin_amdgcn_mfma_f32_16x16x32_bf16(xh[t], wrh, acc[t][cf], 0, 0, 0);
        acc[t][cf] = __builtin_amdgcn_mfma_f32_16x16x32_bf16(xl[t], wrh, acc[t][cf], 0, 0, 0);
        acc[t][cf] = __builtin_amdgcn_mfma_f32_16x16x32_bf16(xh[t], wrl, acc[t][cf], 0, 0, 0);
      }
    }
  }

  // Epilogue: C/D layout col = lane&15, row = (lane>>4)*4 + i (verified).
  const int ocol0 = lane & 15;
  const int orow_off = (lane >> 4) * 4;
#pragma unroll
  for (int cf = 0; cf < 8; ++cf) {
    const int ocol = cf * 16 + ocol0;
    const float b = bias[ocol];
    const float a = alpha[ocol];
#pragma unroll
    for (int t = 0; t < 2; ++t) {
      const int orb = rbase + t * 16 + orow_off;
#pragma unroll
      for (int i = 0; i < 4; ++i) {
        const int orow = orb + i;
        if (orow < n) {
          float v = acc[t][cf][i] + b;
          out[(size_t)orow * 128 + ocol] = v > 0.f ? v : a * v;
        }
      }
    }
  }
}

static void run_layer(const float* hsrc, const float* xdst, const void* src,
                      const void* dst, const int* flag, int E, int n,
                      int* cnt, int* offs, int* eid, int* bsum,
                      unsigned short* meanR, const unsigned short* Wpk,
                      const float* b, const float* a, float* out,
                      hipStream_t stream) {
  int nb = NDIV_UP(n, 1024);
  hipMemsetAsync(cnt, 0, (size_t)n * sizeof(int), stream);
  hist_kernel<<<NDIV_UP(E, 256), 256, 0, stream>>>(dst, flag, cnt, E);
  scan_reduce<<<nb, 256, 0, stream>>>(cnt, n, bsum);
  scan_bsums<<<1, 64, 0, stream>>>(bsum, nb);
  scan_final<<<nb, 256, 0, stream>>>(cnt, n, bsum, offs);
  fill_kernel<<<NDIV_UP(E, 256), 256, 0, stream>>>(src, dst, flag, offs, eid, E);
  gather_mean_kernel<<<NDIV_UP(n, 4), 256, 0, stream>>>(hsrc, offs, eid, meanR, n);
  compute_mfma3_kernel<<<NDIV_UP(n, 128), 256, 0, stream>>>(
      meanR, xdst, Wpk, b, a, out, n);
}

extern "C" void kernel_launch(void* const* d_in, const int* in_sizes, int n_in,
                              void* d_out, int out_size, void* d_ws, size_t ws_size,
                              hipStream_t stream) {
  const float* x = (const float*)d_in[0];
  const void* src1 = d_in[1];
  const void* dst1 = d_in[2];
  const void* src2 = d_in[3];
  const void* dst2 = d_in[4];
  const void* src3 = d_in[5];
  const void* dst3 = d_in[6];
  const float* Wl1 = (const float*)d_in[7];
  const float* Wr1 = (const float*)d_in[8];
  const float* b1  = (const float*)d_in[9];
  const float* a1  = (const float*)d_in[10];
  const float* Wl2 = (const float*)d_in[11];
  const float* Wr2 = (const float*)d_in[12];
  const float* b2  = (const float*)d_in[13];
  const float* a2  = (const float*)d_in[14];
  const float* Wl3 = (const float*)d_in[15];
  const float* Wr3 = (const float*)d_in[16];
  const float* b3  = (const float*)d_in[17];
  const float* a3  = (const float*)d_in[18];

  // ws layout (bytes):
  //   R1: N1*512 (mean1 split rows, then h1 fp32 in-place)
  //   R2: N2*512 (mean2 split rows, then h2 fp32 in-place; mean3 reuses R1)
  //   cnt, offs (N1 ints), eid (E1 ints), bsum (1024 i), flag (64 i), wpk
  unsigned short* R1 = (unsigned short*)d_ws;
  unsigned short* R2 = R1 + (size_t)cN1 * 256;
  int* cnt = (int*)(R2 + (size_t)cN2 * 256);
  int* offs = cnt + cN1;
  int* eid = offs + cN1;
  int* bsum = eid + cE1;
  int* flag = bsum + 1024;
  unsigned short* wpk = (unsigned short*)(flag + 64);

  detect_idx64_kernel<<<1, 64, 0, stream>>>(src1, cE1, (long long)cN0, flag);
  pack_w3_kernel<<<192, 256, 0, stream>>>(Wl1, Wr1, Wl2, Wr2, Wl3, Wr3, wpk);

  // Layer 1: x (N0) -> h1 fp32 in R1
  run_layer(x, x, src1, dst1, flag, cE1, cN1, cnt, offs, eid, bsum,
            R1, wpk, b1, a1, (float*)R1, stream);
  // Layer 2: h1 -> h2 fp32 in R2
  run_layer((const float*)R1, (const float*)R1, src2, dst2, flag, cE2, cN2,
            cnt, offs, eid, bsum, R2, wpk + 65536, b2, a2, (float*)R2, stream);
  // Layer 3: h2 -> out (d_out), mean3 in R1
  run_layer((const float*)R2, (const float*)R2, src3, dst3, flag, cE3, cN3,
            cnt, offs, eid, bsum, R1, wpk + 131072, b3, a3, (float*)d_out, stream);
}

// Round 6
// 427.173 us; speedup vs baseline: 1.2836x; 1.2836x over previous
//
#include <hip/hip_runtime.h>

// GraphSAGE 3-layer encoder.
// One batched CSR build for all 3 layers (hist -> parallel scan -> fill over
// concatenated dst space), then per layer ONE fused kernel:
//   gather-mean (fp32 reg accum) -> split-bf16 -> MFMA (out = mean@Wl+b+x@Wr) -> PReLU.

constexpr int cN0 = 400000, cN1 = 200000, cN2 = 100000, cN3 = 50000;
constexpr int cE1 = 500000, cE2 = 300000, cE3 = 150000;
constexpr int cNT = cN1 + cN2 + cN3;   // 350000 concatenated dst rows
constexpr int cET = cE1 + cE2 + cE3;   // 950000 concatenated edges

#define NDIV_UP(a, b) (((a) + (b) - 1) / (b))

typedef __attribute__((ext_vector_type(8))) short bf16x8;
typedef __attribute__((ext_vector_type(4))) float f32x4;
typedef __attribute__((ext_vector_type(4))) unsigned u32x4;

__device__ __forceinline__ unsigned fbits(float f) {
  return __builtin_bit_cast(unsigned, f);
}
__device__ __forceinline__ float ffrom(unsigned u) {
  return __builtin_bit_cast(float, u);
}
__device__ __forceinline__ unsigned short f2bf(float f) {  // round-to-nearest
  unsigned u = fbits(f);
  unsigned r = u + 0x7FFFu + ((u >> 16) & 1u);
  return (unsigned short)(r >> 16);
}
__device__ __forceinline__ float bf2f(unsigned short h) {
  return ffrom((unsigned)h << 16);
}

// Detect whether index buffers are int64 (JAX x64) or int32 — parallel, 1 wave.
__global__ void detect_idx64_kernel(const long long* __restrict__ p, int E,
                                    long long nmax, int* __restrict__ flag) {
  int t = threadIdx.x;
  int n = E < 512 ? E : 512;
  int bad = 0;
  for (int i = t; i < n; i += 64) {
    long long v = p[i];
    if (v < 0 || v >= nmax) bad = 1;
  }
  unsigned long long b = __ballot(bad);
  if (t == 0) *flag = (b == 0ull) ? 1 : 0;
}

__device__ __forceinline__ int load_idx(const void* p, int i, int flag) {
  return flag ? (int)((const long long*)p)[i] : ((const int*)p)[i];
}

// Histogram over concatenated dst space (layer l's dst offset by segment base).
__global__ void hist3_kernel(const void* __restrict__ d1, const void* __restrict__ d2,
                             const void* __restrict__ d3, const int* __restrict__ flag,
                             int* __restrict__ CNT) {
  int e = blockIdx.x * 256 + threadIdx.x;
  if (e >= cET) return;
  int f = *flag;
  int d;
  if (e < cE1) d = load_idx(d1, e, f);
  else if (e < cE1 + cE2) d = cN1 + load_idx(d2, e - cE1, f);
  else d = cN1 + cN2 + load_idx(d3, e - cE1 - cE2, f);
  atomicAdd(&CNT[d], 1);
}

// ---- exclusive scan over CNT[cNT] -> OFFS[cNT], 1024 items / block ----
__global__ __launch_bounds__(256) void scan_reduce(const int* __restrict__ cnt,
                                                   int n, int* __restrict__ bsum) {
  __shared__ int s[256];
  int t = threadIdx.x;
  int base = blockIdx.x * 1024 + t * 4;
  int v = 0;
  if (base + 3 < n) {
    int4 c = *(const int4*)(cnt + base);
    v = c.x + c.y + c.z + c.w;
  } else {
    for (int i = 0; i < 4; ++i)
      if (base + i < n) v += cnt[base + i];
  }
  s[t] = v;
  __syncthreads();
  for (int off = 128; off > 0; off >>= 1) {
    if (t < off) s[t] += s[t + off];
    __syncthreads();
  }
  if (t == 0) bsum[blockIdx.x] = s[0];
}

// Parallel single-block exclusive scan over up to 512 block-sums.
__global__ __launch_bounds__(256) void scan_bsums(int* __restrict__ bsum, int nb) {
  __shared__ int s[256];
  int t = threadIdx.x;
  int v0 = (2 * t < nb) ? bsum[2 * t] : 0;
  int v1 = (2 * t + 1 < nb) ? bsum[2 * t + 1] : 0;
  int p = v0 + v1;
  s[t] = p;
  __syncthreads();
  for (int off = 1; off < 256; off <<= 1) {
    int x = (t >= off) ? s[t - off] : 0;
    __syncthreads();
    s[t] += x;
    __syncthreads();
  }
  int excl = s[t] - p;
  if (2 * t < nb) bsum[2 * t] = excl;
  if (2 * t + 1 < nb) bsum[2 * t + 1] = excl + v0;
}

__global__ __launch_bounds__(256) void scan_final(const int* __restrict__ cnt,
                                                  int n, const int* __restrict__ bsum,
                                                  int* __restrict__ offs) {
  __shared__ int s[256];
  int t = threadIdx.x;
  int base = blockIdx.x * 1024 + t * 4;
  int v0 = 0, v1 = 0, v2 = 0, v3 = 0;
  if (base + 3 < n) {
    int4 c = *(const int4*)(cnt + base);
    v0 = c.x; v1 = c.y; v2 = c.z; v3 = c.w;
  } else {
    if (base + 0 < n) v0 = cnt[base + 0];
    if (base + 1 < n) v1 = cnt[base + 1];
    if (base + 2 < n) v2 = cnt[base + 2];
  }
  int tsum = v0 + v1 + v2 + v3;
  s[t] = tsum;
  __syncthreads();
  for (int off = 1; off < 256; off <<= 1) {
    int x = (t >= off) ? s[t - off] : 0;
    __syncthreads();
    s[t] += x;
    __syncthreads();
  }
  int excl = s[t] - tsum;
  int o = bsum[blockIdx.x] + excl;
  if (base + 0 < n) offs[base + 0] = o;
  o += v0;
  if (base + 1 < n) offs[base + 1] = o;
  o += v1;
  if (base + 2 < n) offs[base + 2] = o;
  o += v2;
  if (base + 3 < n) offs[base + 3] = o;
}

// Bucket-fill into concatenated EID; post-fill OFFS[d] == pre-fill OFFS[d+1].
__global__ void fill3_kernel(const void* __restrict__ s1, const void* __restrict__ d1,
                             const void* __restrict__ s2, const void* __restrict__ d2,
                             const void* __restrict__ s3, const void* __restrict__ d3,
                             const int* __restrict__ flag,
                             int* __restrict__ OFFS, int* __restrict__ EID) {
  int e = blockIdx.x * 256 + threadIdx.x;
  if (e >= cET) return;
  int f = *flag;
  int s, d;
  if (e < cE1) {
    s = load_idx(s1, e, f);
    d = load_idx(d1, e, f);
  } else if (e < cE1 + cE2) {
    int i = e - cE1;
    s = load_idx(s2, i, f);
    d = cN1 + load_idx(d2, i, f);
  } else {
    int i = e - cE1 - cE2;
    s = load_idx(s3, i, f);
    d = cN1 + cN2 + load_idx(d3, i, f);
  }
  int pos = atomicAdd(&OFFS[d], 1);
  EID[pos] = s;
}

// Pre-pack weights (all 3 layers) into per-lane MFMA B-fragment order,
// split bf16 hi/lo. Per layer: Wlh|Wll|Wrh|Wrl x16384 u16.
// r = ks*4096 + cf*512 + l*8 + j ; k = ks*32+(l>>4)*8+j ; col = cf*16+(l&15).
__global__ void pack_w3_kernel(const float* __restrict__ Wl1, const float* __restrict__ Wr1,
                               const float* __restrict__ Wl2, const float* __restrict__ Wr2,
                               const float* __restrict__ Wl3, const float* __restrict__ Wr3,
                               unsigned short* __restrict__ wpk) {
  int idx = blockIdx.x * 256 + threadIdx.x;
  if (idx >= 3 * 16384) return;
  int L = idx >> 14;
  int r = idx & 16383;
  const float* Wl = L == 0 ? Wl1 : (L == 1 ? Wl2 : Wl3);
  const float* Wr = L == 0 ? Wr1 : (L == 1 ? Wr2 : Wr3);
  unsigned short* o = wpk + L * 65536;
  int j = r & 7, l = (r >> 3) & 63, cf = (r >> 9) & 7, ks = r >> 12;
  int k = ks * 32 + (l >> 4) * 8 + j;
  int col = cf * 16 + (l & 15);
  float vl = Wl[k * 128 + col];
  float vr = Wr[k * 128 + col];
  unsigned short h = f2bf(vl);
  o[r] = h;
  o[16384 + r] = f2bf(vl - bf2f(h));
  h = f2bf(vr);
  o[32768 + r] = h;
  o[49152 + r] = f2bf(vr - bf2f(h));
}

// Fused gather-mean + MFMA. 4 waves/block; wave owns 32 rows (2x 16-row tiles).
// Gather: 4 lanes per row (g = lane>>4 picks k-slice); per edge per ks the 4
// g-lanes cover exactly one 128B line of the source row. Mean accumulates in
// fp32 regs, then truncation-split to bf16 hi/lo. x (the row itself) splits
// in-register per ks. B-fragments load from packed W (L2-resident).
// out must NOT alias hsrc (other blocks gather any row).
__global__ __launch_bounds__(256) void fused_kernel(
    const float* __restrict__ hsrc, const int* __restrict__ OFFS,
    const int* __restrict__ EID, int rowoff,
    const unsigned short* __restrict__ W,
    const float* __restrict__ bias, const float* __restrict__ alpha,
    float* __restrict__ out, int n) {
  const int lane = threadIdx.x & 63;
  const int wv = threadIdx.x >> 6;
  const int rbase = blockIdx.x * 128 + wv * 32;
  const int g = lane >> 4;
  const int r16 = lane & 15;

  bf16x8 mh[2][4], ml[2][4];
#pragma unroll
  for (int t = 0; t < 2; ++t) {
    const int row = rbase + t * 16 + r16;
    float s[4][8];
#pragma unroll
    for (int ks = 0; ks < 4; ++ks)
#pragma unroll
      for (int j = 0; j < 8; ++j) s[ks][j] = 0.f;
    int start = 0, end = 0;
    if (row < n) {
      int gr = rowoff + row;
      start = gr ? OFFS[gr - 1] : 0;
      end = OFFS[gr];
    }
    for (int i = start; i < end; ++i) {
      const float* rp = hsrc + (size_t)EID[i] * 128 + g * 8;
#pragma unroll
      for (int ks = 0; ks < 4; ++ks) {
        const float4 v0 = *(const float4*)(rp + ks * 32);
        const float4 v1 = *(const float4*)(rp + ks * 32 + 4);
        s[ks][0] += v0.x; s[ks][1] += v0.y; s[ks][2] += v0.z; s[ks][3] += v0.w;
        s[ks][4] += v1.x; s[ks][5] += v1.y; s[ks][6] += v1.z; s[ks][7] += v1.w;
      }
    }
    const float inv = (end > start) ? 1.0f / (float)(end - start) : 0.0f;
#pragma unroll
    for (int ks = 0; ks < 4; ++ks) {
      u32x4 hwv, lwv;
#pragma unroll
      for (int p = 0; p < 4; ++p) {
        float me = s[ks][2 * p] * inv, mo = s[ks][2 * p + 1] * inv;
        unsigned ue = fbits(me), uo = fbits(mo);
        hwv[p] = (ue >> 16) | (uo & 0xFFFF0000u);
        float re = me - ffrom(ue & 0xFFFF0000u);
        float ro = mo - ffrom(uo & 0xFFFF0000u);
        lwv[p] = (fbits(re) >> 16) | (fbits(ro) & 0xFFFF0000u);
      }
      mh[t][ks] = __builtin_bit_cast(bf16x8, hwv);
      ml[t][ks] = __builtin_bit_cast(bf16x8, lwv);
    }
  }

  f32x4 acc[2][8] = {};
  for (int ks = 0; ks < 4; ++ks) {
    bf16x8 xh[2], xl[2];
#pragma unroll
    for (int t = 0; t < 2; ++t) {
      const int row = rbase + t * 16 + r16;
      if (row < n) {
        const float* xp = hsrc + (size_t)row * 128 + ks * 32 + g * 8;
        float xv[8];
        *(float4*)&xv[0] = *(const float4*)(xp);
        *(float4*)&xv[4] = *(const float4*)(xp + 4);
        u32x4 hwv, lwv;
#pragma unroll
        for (int p = 0; p < 4; ++p) {
          unsigned ue = fbits(xv[2 * p]), uo = fbits(xv[2 * p + 1]);
          hwv[p] = (ue >> 16) | (uo & 0xFFFF0000u);
          float re = xv[2 * p] - ffrom(ue & 0xFFFF0000u);
          float ro = xv[2 * p + 1] - ffrom(uo & 0xFFFF0000u);
          lwv[p] = (fbits(re) >> 16) | (fbits(ro) & 0xFFFF0000u);
        }
        xh[t] = __builtin_bit_cast(bf16x8, hwv);
        xl[t] = __builtin_bit_cast(bf16x8, lwv);
      } else {
        xh[t] = (bf16x8)0;
        xl[t] = (bf16x8)0;
      }
    }
    const unsigned short* wb = W + (size_t)ks * 4096 + (size_t)lane * 8;
#pragma unroll
    for (int cf = 0; cf < 8; ++cf) {
      const unsigned short* wp = wb + cf * 512;
      bf16x8 wlh = *(const bf16x8*)(wp);
      bf16x8 wll = *(const bf16x8*)(wp + 16384);
      bf16x8 wrh = *(const bf16x8*)(wp + 32768);
      bf16x8 wrl = *(const bf16x8*)(wp + 49152);
#pragma unroll
      for (int t = 0; t < 2; ++t) {
        acc[t][cf] = __builtin_amdgcn_mfma_f32_16x16x32_bf16(mh[t][ks], wlh, acc[t][cf], 0, 0, 0);
        acc[t][cf] = __builtin_amdgcn_mfma_f32_16x16x32_bf16(ml[t][ks], wlh, acc[t][cf], 0, 0, 0);
        acc[t][cf] = __builtin_amdgcn_mfma_f32_16x16x32_bf16(mh[t][ks], wll, acc[t][cf], 0, 0, 0);
        acc[t][cf] = __builtin_amdgcn_mfma_f32_16x16x32_bf16(xh[t], wrh, acc[t][cf], 0, 0, 0);
        acc[t][cf] = __builtin_amdgcn_mfma_f32_16x16x32_bf16(xl[t], wrh, acc[t][cf], 0, 0, 0);
        acc[t][cf] = __builtin_amdgcn_mfma_f32_16x16x32_bf16(xh[t], wrl, acc[t][cf], 0, 0, 0);
      }
    }
  }

  // Epilogue: C/D layout col = lane&15, row = (lane>>4)*4 + i (verified).
  const int ocol0 = lane & 15;
  const int orow_off = (lane >> 4) * 4;
#pragma unroll
  for (int cf = 0; cf < 8; ++cf) {
    const int ocol = cf * 16 + ocol0;
    const float b = bias[ocol];
    const float a = alpha[ocol];
#pragma unroll
    for (int t = 0; t < 2; ++t) {
      const int orb = rbase + t * 16 + orow_off;
#pragma unroll
      for (int i = 0; i < 4; ++i) {
        const int orow = orb + i;
        if (orow < n) {
          float v = acc[t][cf][i] + b;
          out[(size_t)orow * 128 + ocol] = v > 0.f ? v : a * v;
        }
      }
    }
  }
}

extern "C" void kernel_launch(void* const* d_in, const int* in_sizes, int n_in,
                              void* d_out, int out_size, void* d_ws, size_t ws_size,
                              hipStream_t stream) {
  const float* x = (const float*)d_in[0];
  const void* src1 = d_in[1];
  const void* dst1 = d_in[2];
  const void* src2 = d_in[3];
  const void* dst2 = d_in[4];
  const void* src3 = d_in[5];
  const void* dst3 = d_in[6];
  const float* Wl1 = (const float*)d_in[7];
  const float* Wr1 = (const float*)d_in[8];
  const float* b1  = (const float*)d_in[9];
  const float* a1  = (const float*)d_in[10];
  const float* Wl2 = (const float*)d_in[11];
  const float* Wr2 = (const float*)d_in[12];
  const float* b2  = (const float*)d_in[13];
  const float* a2  = (const float*)d_in[14];
  const float* Wl3 = (const float*)d_in[15];
  const float* Wr3 = (const float*)d_in[16];
  const float* b3  = (const float*)d_in[17];
  const float* a3  = (const float*)d_in[18];

  // ws layout: R1 (N1*128 f), R2 (N2*128 f), CNT (cNT i), OFFS (cNT i),
  //            EID (cET i), bsum (1024 i), flag (64 i), wpk (3*65536 u16)
  float* R1 = (float*)d_ws;
  float* R2 = R1 + (size_t)cN1 * 128;
  int* CNT = (int*)(R2 + (size_t)cN2 * 128);
  int* OFFS = CNT + cNT;
  int* EID = OFFS + cNT;
  int* bsum = EID + cET;
  int* flag = bsum + 1024;
  unsigned short* wpk = (unsigned short*)(flag + 64);

  const int nb = NDIV_UP(cNT, 1024);  // 342 <= 512

  detect_idx64_kernel<<<1, 64, 0, stream>>>((const long long*)src1, cE1,
                                            (long long)cN0, flag);
  pack_w3_kernel<<<192, 256, 0, stream>>>(Wl1, Wr1, Wl2, Wr2, Wl3, Wr3, wpk);
  hipMemsetAsync(CNT, 0, (size_t)cNT * sizeof(int), stream);
  hist3_kernel<<<NDIV_UP(cET, 256), 256, 0, stream>>>(dst1, dst2, dst3, flag, CNT);
  scan_reduce<<<nb, 256, 0, stream>>>(CNT, cNT, bsum);
  scan_bsums<<<1, 256, 0, stream>>>(bsum, nb);
  scan_final<<<nb, 256, 0, stream>>>(CNT, cNT, bsum, OFFS);
  fill3_kernel<<<NDIV_UP(cET, 256), 256, 0, stream>>>(src1, dst1, src2, dst2,
                                                      src3, dst3, flag, OFFS, EID);

  // Layer 1: x -> R1 ; Layer 2: R1 -> R2 ; Layer 3: R2 -> d_out
  fused_kernel<<<NDIV_UP(cN1, 128), 256, 0, stream>>>(
      x, OFFS, EID, 0, wpk, b1, a1, R1, cN1);
  fused_kernel<<<NDIV_UP(cN2, 128), 256, 0, stream>>>(
      R1, OFFS, EID, cN1, wpk + 65536, b2, a2, R2, cN2);
  fused_kernel<<<NDIV_UP(cN3, 128), 256, 0, stream>>>(
      R2, OFFS, EID, cN1 + cN2, wpk + 131072, b3, a3, (float*)d_out, cN3);
}

// Round 7
// 410.145 us; speedup vs baseline: 1.3369x; 1.0415x over previous
//
#include <hip/hip_runtime.h>

// GraphSAGE 3-layer encoder.
// One batched CSR build for all 3 layers (hist -> parallel scan -> fill over
// concatenated dst space), then per layer ONE fused kernel:
//   gather-mean (fp32 reg accum) -> split-bf16 A x RTN-bf16 W MFMA -> PReLU.
// W is plain bf16 (RTN): A-side stays split (hi+lo), so per-product error is
// dominated by W quantization (2^-9 rel) -- measured harness floor is 2^-8.

constexpr int cN0 = 400000, cN1 = 200000, cN2 = 100000, cN3 = 50000;
constexpr int cE1 = 500000, cE2 = 300000, cE3 = 150000;
constexpr int cNT = cN1 + cN2 + cN3;   // 350000 concatenated dst rows
constexpr int cET = cE1 + cE2 + cE3;   // 950000 concatenated edges

#define NDIV_UP(a, b) (((a) + (b) - 1) / (b))

typedef __attribute__((ext_vector_type(8))) short bf16x8;
typedef __attribute__((ext_vector_type(4))) float f32x4;
typedef __attribute__((ext_vector_type(4))) unsigned u32x4;

__device__ __forceinline__ unsigned fbits(float f) {
  return __builtin_bit_cast(unsigned, f);
}
__device__ __forceinline__ float ffrom(unsigned u) {
  return __builtin_bit_cast(float, u);
}
__device__ __forceinline__ unsigned short f2bf(float f) {  // round-to-nearest
  unsigned u = fbits(f);
  unsigned r = u + 0x7FFFu + ((u >> 16) & 1u);
  return (unsigned short)(r >> 16);
}
__device__ __forceinline__ float bf2f(unsigned short h) {
  return ffrom((unsigned)h << 16);
}

// Detect whether index buffers are int64 (JAX x64) or int32 — parallel, 1 wave.
__global__ void detect_idx64_kernel(const long long* __restrict__ p, int E,
                                    long long nmax, int* __restrict__ flag) {
  int t = threadIdx.x;
  int n = E < 512 ? E : 512;
  int bad = 0;
  for (int i = t; i < n; i += 64) {
    long long v = p[i];
    if (v < 0 || v >= nmax) bad = 1;
  }
  unsigned long long b = __ballot(bad);
  if (t == 0) *flag = (b == 0ull) ? 1 : 0;
}

__device__ __forceinline__ int load_idx(const void* p, int i, int flag) {
  return flag ? (int)((const long long*)p)[i] : ((const int*)p)[i];
}

// Histogram over concatenated dst space (layer l's dst offset by segment base).
__global__ void hist3_kernel(const void* __restrict__ d1, const void* __restrict__ d2,
                             const void* __restrict__ d3, const int* __restrict__ flag,
                             int* __restrict__ CNT) {
  int e = blockIdx.x * 256 + threadIdx.x;
  if (e >= cET) return;
  int f = *flag;
  int d;
  if (e < cE1) d = load_idx(d1, e, f);
  else if (e < cE1 + cE2) d = cN1 + load_idx(d2, e - cE1, f);
  else d = cN1 + cN2 + load_idx(d3, e - cE1 - cE2, f);
  atomicAdd(&CNT[d], 1);
}

// ---- exclusive scan over CNT[cNT] -> OFFS[cNT], 1024 items / block ----
__global__ __launch_bounds__(256) void scan_reduce(const int* __restrict__ cnt,
                                                   int n, int* __restrict__ bsum) {
  __shared__ int s[256];
  int t = threadIdx.x;
  int base = blockIdx.x * 1024 + t * 4;
  int v = 0;
  if (base + 3 < n) {
    int4 c = *(const int4*)(cnt + base);
    v = c.x + c.y + c.z + c.w;
  } else {
    for (int i = 0; i < 4; ++i)
      if (base + i < n) v += cnt[base + i];
  }
  s[t] = v;
  __syncthreads();
  for (int off = 128; off > 0; off >>= 1) {
    if (t < off) s[t] += s[t + off];
    __syncthreads();
  }
  if (t == 0) bsum[blockIdx.x] = s[0];
}

// Parallel single-block exclusive scan over up to 512 block-sums.
__global__ __launch_bounds__(256) void scan_bsums(int* __restrict__ bsum, int nb) {
  __shared__ int s[256];
  int t = threadIdx.x;
  int v0 = (2 * t < nb) ? bsum[2 * t] : 0;
  int v1 = (2 * t + 1 < nb) ? bsum[2 * t + 1] : 0;
  int p = v0 + v1;
  s[t] = p;
  __syncthreads();
  for (int off = 1; off < 256; off <<= 1) {
    int x = (t >= off) ? s[t - off] : 0;
    __syncthreads();
    s[t] += x;
    __syncthreads();
  }
  int excl = s[t] - p;
  if (2 * t < nb) bsum[2 * t] = excl;
  if (2 * t + 1 < nb) bsum[2 * t + 1] = excl + v0;
}

__global__ __launch_bounds__(256) void scan_final(const int* __restrict__ cnt,
                                                  int n, const int* __restrict__ bsum,
                                                  int* __restrict__ offs) {
  __shared__ int s[256];
  int t = threadIdx.x;
  int base = blockIdx.x * 1024 + t * 4;
  int v0 = 0, v1 = 0, v2 = 0, v3 = 0;
  if (base + 3 < n) {
    int4 c = *(const int4*)(cnt + base);
    v0 = c.x; v1 = c.y; v2 = c.z; v3 = c.w;
  } else {
    if (base + 0 < n) v0 = cnt[base + 0];
    if (base + 1 < n) v1 = cnt[base + 1];
    if (base + 2 < n) v2 = cnt[base + 2];
  }
  int tsum = v0 + v1 + v2 + v3;
  s[t] = tsum;
  __syncthreads();
  for (int off = 1; off < 256; off <<= 1) {
    int x = (t >= off) ? s[t - off] : 0;
    __syncthreads();
    s[t] += x;
    __syncthreads();
  }
  int excl = s[t] - tsum;
  int o = bsum[blockIdx.x] + excl;
  if (base + 0 < n) offs[base + 0] = o;
  o += v0;
  if (base + 1 < n) offs[base + 1] = o;
  o += v1;
  if (base + 2 < n) offs[base + 2] = o;
  o += v2;
  if (base + 3 < n) offs[base + 3] = o;
}

// Bucket-fill into concatenated EID; post-fill OFFS[d] == pre-fill OFFS[d+1].
__global__ void fill3_kernel(const void* __restrict__ s1, const void* __restrict__ d1,
                             const void* __restrict__ s2, const void* __restrict__ d2,
                             const void* __restrict__ s3, const void* __restrict__ d3,
                             const int* __restrict__ flag,
                             int* __restrict__ OFFS, int* __restrict__ EID) {
  int e = blockIdx.x * 256 + threadIdx.x;
  if (e >= cET) return;
  int f = *flag;
  int s, d;
  if (e < cE1) {
    s = load_idx(s1, e, f);
    d = load_idx(d1, e, f);
  } else if (e < cE1 + cE2) {
    int i = e - cE1;
    s = load_idx(s2, i, f);
    d = cN1 + load_idx(d2, i, f);
  } else {
    int i = e - cE1 - cE2;
    s = load_idx(s3, i, f);
    d = cN1 + cN2 + load_idx(d3, i, f);
  }
  int pos = atomicAdd(&OFFS[d], 1);
  EID[pos] = s;
}

// Pre-pack weights (all 3 layers) into per-lane MFMA B-fragment order,
// RTN bf16 (no split). Per layer: Wl|Wr x16384 u16 (64 KB).
// r = ks*4096 + cf*512 + l*8 + j ; k = ks*32+(l>>4)*8+j ; col = cf*16+(l&15).
__global__ void pack_w3_kernel(const float* __restrict__ Wl1, const float* __restrict__ Wr1,
                               const float* __restrict__ Wl2, const float* __restrict__ Wr2,
                               const float* __restrict__ Wl3, const float* __restrict__ Wr3,
                               unsigned short* __restrict__ wpk) {
  int idx = blockIdx.x * 256 + threadIdx.x;
  if (idx >= 3 * 16384) return;
  int L = idx >> 14;
  int r = idx & 16383;
  const float* Wl = L == 0 ? Wl1 : (L == 1 ? Wl2 : Wl3);
  const float* Wr = L == 0 ? Wr1 : (L == 1 ? Wr2 : Wr3);
  unsigned short* o = wpk + L * 32768;
  int j = r & 7, l = (r >> 3) & 63, cf = (r >> 9) & 7, ks = r >> 12;
  int k = ks * 32 + (l >> 4) * 8 + j;
  int col = cf * 16 + (l & 15);
  o[r] = f2bf(Wl[k * 128 + col]);
  o[16384 + r] = f2bf(Wr[k * 128 + col]);
}

// Fused gather-mean + MFMA. 4 waves/block; wave owns 32 rows (2x 16-row tiles).
// Gather: 4 lanes per row (g = lane>>4 picks k-slice); mean accumulates in
// fp32 regs, truncation-split to bf16 hi/lo (A-side stays ~fp32-exact).
// x (the row itself) splits in-register per ks. W is RTN bf16 (single term):
//   acc += mh@Wl + ml@Wl + xh@Wr + xl@Wr      (4 MFMA per cf per tile)
// B-fragments load from packed W (L2-resident). out must NOT alias hsrc.
__global__ __launch_bounds__(256) void fused_kernel(
    const float* __restrict__ hsrc, const int* __restrict__ OFFS,
    const int* __restrict__ EID, int rowoff,
    const unsigned short* __restrict__ W,
    const float* __restrict__ bias, const float* __restrict__ alpha,
    float* __restrict__ out, int n) {
  const int lane = threadIdx.x & 63;
  const int wv = threadIdx.x >> 6;
  const int rbase = blockIdx.x * 128 + wv * 32;
  const int g = lane >> 4;
  const int r16 = lane & 15;

  bf16x8 mh[2][4], ml[2][4];
#pragma unroll
  for (int t = 0; t < 2; ++t) {
    const int row = rbase + t * 16 + r16;
    float s[4][8];
#pragma unroll
    for (int ks = 0; ks < 4; ++ks)
#pragma unroll
      for (int j = 0; j < 8; ++j) s[ks][j] = 0.f;
    int start = 0, end = 0;
    if (row < n) {
      int gr = rowoff + row;
      start = gr ? OFFS[gr - 1] : 0;
      end = OFFS[gr];
    }
    for (int i = start; i < end; ++i) {
      const float* rp = hsrc + (size_t)EID[i] * 128 + g * 8;
#pragma unroll
      for (int ks = 0; ks < 4; ++ks) {
        const float4 v0 = *(const float4*)(rp + ks * 32);
        const float4 v1 = *(const float4*)(rp + ks * 32 + 4);
        s[ks][0] += v0.x; s[ks][1] += v0.y; s[ks][2] += v0.z; s[ks][3] += v0.w;
        s[ks][4] += v1.x; s[ks][5] += v1.y; s[ks][6] += v1.z; s[ks][7] += v1.w;
      }
    }
    const float inv = (end > start) ? 1.0f / (float)(end - start) : 0.0f;
#pragma unroll
    for (int ks = 0; ks < 4; ++ks) {
      u32x4 hwv, lwv;
#pragma unroll
      for (int p = 0; p < 4; ++p) {
        float me = s[ks][2 * p] * inv, mo = s[ks][2 * p + 1] * inv;
        unsigned ue = fbits(me), uo = fbits(mo);
        hwv[p] = (ue >> 16) | (uo & 0xFFFF0000u);
        float re = me - ffrom(ue & 0xFFFF0000u);
        float ro = mo - ffrom(uo & 0xFFFF0000u);
        lwv[p] = (fbits(re) >> 16) | (fbits(ro) & 0xFFFF0000u);
      }
      mh[t][ks] = __builtin_bit_cast(bf16x8, hwv);
      ml[t][ks] = __builtin_bit_cast(bf16x8, lwv);
    }
  }

  f32x4 acc[2][8] = {};
  for (int ks = 0; ks < 4; ++ks) {
    bf16x8 xh[2], xl[2];
#pragma unroll
    for (int t = 0; t < 2; ++t) {
      const int row = rbase + t * 16 + r16;
      if (row < n) {
        const float* xp = hsrc + (size_t)row * 128 + ks * 32 + g * 8;
        float xv[8];
        *(float4*)&xv[0] = *(const float4*)(xp);
        *(float4*)&xv[4] = *(const float4*)(xp + 4);
        u32x4 hwv, lwv;
#pragma unroll
        for (int p = 0; p < 4; ++p) {
          unsigned ue = fbits(xv[2 * p]), uo = fbits(xv[2 * p + 1]);
          hwv[p] = (ue >> 16) | (uo & 0xFFFF0000u);
          float re = xv[2 * p] - ffrom(ue & 0xFFFF0000u);
          float ro = xv[2 * p + 1] - ffrom(uo & 0xFFFF0000u);
          lwv[p] = (fbits(re) >> 16) | (fbits(ro) & 0xFFFF0000u);
        }
        xh[t] = __builtin_bit_cast(bf16x8, hwv);
        xl[t] = __builtin_bit_cast(bf16x8, lwv);
      } else {
        xh[t] = (bf16x8)0;
        xl[t] = (bf16x8)0;
      }
    }
    const unsigned short* wb = W + (size_t)ks * 4096 + (size_t)lane * 8;
#pragma unroll
    for (int cf = 0; cf < 8; ++cf) {
      const unsigned short* wp = wb + cf * 512;
      bf16x8 wl = *(const bf16x8*)(wp);
      bf16x8 wr = *(const bf16x8*)(wp + 16384);
#pragma unroll
      for (int t = 0; t < 2; ++t) {
        acc[t][cf] = __builtin_amdgcn_mfma_f32_16x16x32_bf16(mh[t][ks], wl, acc[t][cf], 0, 0, 0);
        acc[t][cf] = __builtin_amdgcn_mfma_f32_16x16x32_bf16(ml[t][ks], wl, acc[t][cf], 0, 0, 0);
        acc[t][cf] = __builtin_amdgcn_mfma_f32_16x16x32_bf16(xh[t], wr, acc[t][cf], 0, 0, 0);
        acc[t][cf] = __builtin_amdgcn_mfma_f32_16x16x32_bf16(xl[t], wr, acc[t][cf], 0, 0, 0);
      }
    }
  }

  // Epilogue: C/D layout col = lane&15, row = (lane>>4)*4 + i (verified).
  const int ocol0 = lane & 15;
  const int orow_off = (lane >> 4) * 4;
#pragma unroll
  for (int cf = 0; cf < 8; ++cf) {
    const int ocol = cf * 16 + ocol0;
    const float b = bias[ocol];
    const float a = alpha[ocol];
#pragma unroll
    for (int t = 0; t < 2; ++t) {
      const int orb = rbase + t * 16 + orow_off;
#pragma unroll
      for (int i = 0; i < 4; ++i) {
        const int orow = orb + i;
        if (orow < n) {
          float v = acc[t][cf][i] + b;
          out[(size_t)orow * 128 + ocol] = v > 0.f ? v : a * v;
        }
      }
    }
  }
}

extern "C" void kernel_launch(void* const* d_in, const int* in_sizes, int n_in,
                              void* d_out, int out_size, void* d_ws, size_t ws_size,
                              hipStream_t stream) {
  const float* x = (const float*)d_in[0];
  const void* src1 = d_in[1];
  const void* dst1 = d_in[2];
  const void* src2 = d_in[3];
  const void* dst2 = d_in[4];
  const void* src3 = d_in[5];
  const void* dst3 = d_in[6];
  const float* Wl1 = (const float*)d_in[7];
  const float* Wr1 = (const float*)d_in[8];
  const float* b1  = (const float*)d_in[9];
  const float* a1  = (const float*)d_in[10];
  const float* Wl2 = (const float*)d_in[11];
  const float* Wr2 = (const float*)d_in[12];
  const float* b2  = (const float*)d_in[13];
  const float* a2  = (const float*)d_in[14];
  const float* Wl3 = (const float*)d_in[15];
  const float* Wr3 = (const float*)d_in[16];
  const float* b3  = (const float*)d_in[17];
  const float* a3  = (const float*)d_in[18];

  // ws layout: R1 (N1*128 f), R2 (N2*128 f), CNT (cNT i), OFFS (cNT i),
  //            EID (cET i), bsum (1024 i), flag (64 i), wpk (3*32768 u16)
  float* R1 = (float*)d_ws;
  float* R2 = R1 + (size_t)cN1 * 128;
  int* CNT = (int*)(R2 + (size_t)cN2 * 128);
  int* OFFS = CNT + cNT;
  int* EID = OFFS + cNT;
  int* bsum = EID + cET;
  int* flag = bsum + 1024;
  unsigned short* wpk = (unsigned short*)(flag + 64);

  const int nb = NDIV_UP(cNT, 1024);  // 342 <= 512

  detect_idx64_kernel<<<1, 64, 0, stream>>>((const long long*)src1, cE1,
                                            (long long)cN0, flag);
  pack_w3_kernel<<<192, 256, 0, stream>>>(Wl1, Wr1, Wl2, Wr2, Wl3, Wr3, wpk);
  hipMemsetAsync(CNT, 0, (size_t)cNT * sizeof(int), stream);
  hist3_kernel<<<NDIV_UP(cET, 256), 256, 0, stream>>>(dst1, dst2, dst3, flag, CNT);
  scan_reduce<<<nb, 256, 0, stream>>>(CNT, cNT, bsum);
  scan_bsums<<<1, 256, 0, stream>>>(bsum, nb);
  scan_final<<<nb, 256, 0, stream>>>(CNT, cNT, bsum, OFFS);
  fill3_kernel<<<NDIV_UP(cET, 256), 256, 0, stream>>>(src1, dst1, src2, dst2,
                                                      src3, dst3, flag, OFFS, EID);

  // Layer 1: x -> R1 ; Layer 2: R1 -> R2 ; Layer 3: R2 -> d_out
  fused_kernel<<<NDIV_UP(cN1, 128), 256, 0, stream>>>(
      x, OFFS, EID, 0, wpk, b1, a1, R1, cN1);
  fused_kernel<<<NDIV_UP(cN2, 128), 256, 0, stream>>>(
      R1, OFFS, EID, cN1, wpk + 32768, b2, a2, R2, cN2);
  fused_kernel<<<NDIV_UP(cN3, 128), 256, 0, stream>>>(
      R2, OFFS, EID, cN1 + cN2, wpk + 65536, b3, a3, (float*)d_out, cN3);
}

// Round 8
// 397.488 us; speedup vs baseline: 1.3795x; 1.0318x over previous
//
#include <hip/hip_runtime.h>

// GraphSAGE 3-layer encoder, bf16 feature pipeline.
// Batched CSR build (hist -> scan -> fill, concatenated dst space), then per
// layer: gather-mean (one WAVE per dst row, contiguous row reads, fp32 accum,
// bf16 row out) -> GEMM (MFMA bf16: out = mean@Wl + b + x@Wr, PReLU).
// Intermediates h1/h2 and means are bf16 rows (256 B); final out fp32.

constexpr int cN0 = 400000, cN1 = 200000, cN2 = 100000, cN3 = 50000;
constexpr int cE1 = 500000, cE2 = 300000, cE3 = 150000;
constexpr int cNT = cN1 + cN2 + cN3;   // 350000 concatenated dst rows
constexpr int cET = cE1 + cE2 + cE3;   // 950000 concatenated edges

#define NDIV_UP(a, b) (((a) + (b) - 1) / (b))

typedef __attribute__((ext_vector_type(8))) short bf16x8;
typedef __attribute__((ext_vector_type(4))) float f32x4;
typedef __attribute__((ext_vector_type(4))) unsigned u32x4;

__device__ __forceinline__ unsigned fbits(float f) {
  return __builtin_bit_cast(unsigned, f);
}
__device__ __forceinline__ float ffrom(unsigned u) {
  return __builtin_bit_cast(float, u);
}
__device__ __forceinline__ unsigned short f2bf(float f) {  // round-to-nearest
  unsigned u = fbits(f);
  unsigned r = u + 0x7FFFu + ((u >> 16) & 1u);
  return (unsigned short)(r >> 16);
}

// Detect whether index buffers are int64 (JAX x64) or int32 — parallel, 1 wave.
__global__ void detect_idx64_kernel(const long long* __restrict__ p, int E,
                                    long long nmax, int* __restrict__ flag) {
  int t = threadIdx.x;
  int n = E < 512 ? E : 512;
  int bad = 0;
  for (int i = t; i < n; i += 64) {
    long long v = p[i];
    if (v < 0 || v >= nmax) bad = 1;
  }
  unsigned long long b = __ballot(bad);
  if (t == 0) *flag = (b == 0ull) ? 1 : 0;
}

__device__ __forceinline__ int load_idx(const void* p, int i, int flag) {
  return flag ? (int)((const long long*)p)[i] : ((const int*)p)[i];
}

// Histogram over concatenated dst space.
__global__ void hist3_kernel(const void* __restrict__ d1, const void* __restrict__ d2,
                             const void* __restrict__ d3, const int* __restrict__ flag,
                             int* __restrict__ CNT) {
  int e = blockIdx.x * 256 + threadIdx.x;
  if (e >= cET) return;
  int f = *flag;
  int d;
  if (e < cE1) d = load_idx(d1, e, f);
  else if (e < cE1 + cE2) d = cN1 + load_idx(d2, e - cE1, f);
  else d = cN1 + cN2 + load_idx(d3, e - cE1 - cE2, f);
  atomicAdd(&CNT[d], 1);
}

// ---- exclusive scan over CNT[cNT] -> OFFS[cNT], 1024 items / block ----
__global__ __launch_bounds__(256) void scan_reduce(const int* __restrict__ cnt,
                                                   int n, int* __restrict__ bsum) {
  __shared__ int s[256];
  int t = threadIdx.x;
  int base = blockIdx.x * 1024 + t * 4;
  int v = 0;
  if (base + 3 < n) {
    int4 c = *(const int4*)(cnt + base);
    v = c.x + c.y + c.z + c.w;
  } else {
    for (int i = 0; i < 4; ++i)
      if (base + i < n) v += cnt[base + i];
  }
  s[t] = v;
  __syncthreads();
  for (int off = 128; off > 0; off >>= 1) {
    if (t < off) s[t] += s[t + off];
    __syncthreads();
  }
  if (t == 0) bsum[blockIdx.x] = s[0];
}

// Parallel single-block exclusive scan over up to 512 block-sums.
__global__ __launch_bounds__(256) void scan_bsums(int* __restrict__ bsum, int nb) {
  __shared__ int s[256];
  int t = threadIdx.x;
  int v0 = (2 * t < nb) ? bsum[2 * t] : 0;
  int v1 = (2 * t + 1 < nb) ? bsum[2 * t + 1] : 0;
  int p = v0 + v1;
  s[t] = p;
  __syncthreads();
  for (int off = 1; off < 256; off <<= 1) {
    int x = (t >= off) ? s[t - off] : 0;
    __syncthreads();
    s[t] += x;
    __syncthreads();
  }
  int excl = s[t] - p;
  if (2 * t < nb) bsum[2 * t] = excl;
  if (2 * t + 1 < nb) bsum[2 * t + 1] = excl + v0;
}

__global__ __launch_bounds__(256) void scan_final(const int* __restrict__ cnt,
                                                  int n, const int* __restrict__ bsum,
                                                  int* __restrict__ offs) {
  __shared__ int s[256];
  int t = threadIdx.x;
  int base = blockIdx.x * 1024 + t * 4;
  int v0 = 0, v1 = 0, v2 = 0, v3 = 0;
  if (base + 3 < n) {
    int4 c = *(const int4*)(cnt + base);
    v0 = c.x; v1 = c.y; v2 = c.z; v3 = c.w;
  } else {
    if (base + 0 < n) v0 = cnt[base + 0];
    if (base + 1 < n) v1 = cnt[base + 1];
    if (base + 2 < n) v2 = cnt[base + 2];
  }
  int tsum = v0 + v1 + v2 + v3;
  s[t] = tsum;
  __syncthreads();
  for (int off = 1; off < 256; off <<= 1) {
    int x = (t >= off) ? s[t - off] : 0;
    __syncthreads();
    s[t] += x;
    __syncthreads();
  }
  int excl = s[t] - tsum;
  int o = bsum[blockIdx.x] + excl;
  if (base + 0 < n) offs[base + 0] = o;
  o += v0;
  if (base + 1 < n) offs[base + 1] = o;
  o += v1;
  if (base + 2 < n) offs[base + 2] = o;
  o += v2;
  if (base + 3 < n) offs[base + 3] = o;
}

// Bucket-fill into concatenated EID; post-fill OFFS[d] == pre-fill OFFS[d+1].
__global__ void fill3_kernel(const void* __restrict__ s1, const void* __restrict__ d1,
                             const void* __restrict__ s2, const void* __restrict__ d2,
                             const void* __restrict__ s3, const void* __restrict__ d3,
                             const int* __restrict__ flag,
                             int* __restrict__ OFFS, int* __restrict__ EID) {
  int e = blockIdx.x * 256 + threadIdx.x;
  if (e >= cET) return;
  int f = *flag;
  int s, d;
  if (e < cE1) {
    s = load_idx(s1, e, f);
    d = load_idx(d1, e, f);
  } else if (e < cE1 + cE2) {
    int i = e - cE1;
    s = load_idx(s2, i, f);
    d = cN1 + load_idx(d2, i, f);
  } else {
    int i = e - cE1 - cE2;
    s = load_idx(s3, i, f);
    d = cN1 + cN2 + load_idx(d3, i, f);
  }
  int pos = atomicAdd(&OFFS[d], 1);
  EID[pos] = s;
}

// Pre-pack weights (all 3 layers) into per-lane MFMA B-fragment order, RTN
// bf16. Per layer: Wl|Wr x16384 u16 (64 KB).
// r = ks*4096 + cf*512 + l*8 + j ; k = ks*32+(l>>4)*8+j ; col = cf*16+(l&15).
__global__ void pack_w3_kernel(const float* __restrict__ Wl1, const float* __restrict__ Wr1,
                               const float* __restrict__ Wl2, const float* __restrict__ Wr2,
                               const float* __restrict__ Wl3, const float* __restrict__ Wr3,
                               unsigned short* __restrict__ wpk) {
  int idx = blockIdx.x * 256 + threadIdx.x;
  if (idx >= 3 * 16384) return;
  int L = idx >> 14;
  int r = idx & 16383;
  const float* Wl = L == 0 ? Wl1 : (L == 1 ? Wl2 : Wl3);
  const float* Wr = L == 0 ? Wr1 : (L == 1 ? Wr2 : Wr3);
  unsigned short* o = wpk + L * 32768;
  int j = r & 7, l = (r >> 3) & 63, cf = (r >> 9) & 7, ks = r >> 12;
  int k = ks * 32 + (l >> 4) * 8 + j;
  int col = cf * 16 + (l & 15);
  o[r] = f2bf(Wl[k * 128 + col]);
  o[16384 + r] = f2bf(Wr[k * 128 + col]);
}

// Gather-mean: ONE WAVE per dst row. Lane owns cols 2l,2l+1. Each edge is a
// fully contiguous row read (512B fp32 / 256B bf16 per instruction). fp32
// accumulate, mean, RTN-bf16 row out (256B contiguous).
template <bool SRCF32>
__global__ __launch_bounds__(256) void gather_kernel(
    const void* __restrict__ hsrc, const int* __restrict__ OFFS,
    const int* __restrict__ EID, int rowoff,
    unsigned short* __restrict__ meanB, int n) {
  int row = blockIdx.x * 4 + (threadIdx.x >> 6);
  if (row >= n) return;
  int lane = threadIdx.x & 63;
  int gr = rowoff + row;
  int start = gr ? OFFS[gr - 1] : 0;
  int end = OFFS[gr];
  float a0 = 0.f, a1 = 0.f, b0 = 0.f, b1 = 0.f;
  int i = start;
  for (; i + 1 < end; i += 2) {
    int s0 = EID[i], s1 = EID[i + 1];
    if (SRCF32) {
      float2 v0 = *(const float2*)((const float*)hsrc + (size_t)s0 * 128 + lane * 2);
      float2 v1 = *(const float2*)((const float*)hsrc + (size_t)s1 * 128 + lane * 2);
      a0 += v0.x; a1 += v0.y;
      b0 += v1.x; b1 += v1.y;
    } else {
      unsigned u0 = *(const unsigned*)((const unsigned short*)hsrc + (size_t)s0 * 128 + lane * 2);
      unsigned u1 = *(const unsigned*)((const unsigned short*)hsrc + (size_t)s1 * 128 + lane * 2);
      a0 += ffrom(u0 << 16); a1 += ffrom(u0 & 0xFFFF0000u);
      b0 += ffrom(u1 << 16); b1 += ffrom(u1 & 0xFFFF0000u);
    }
  }
  if (i < end) {
    int s0 = EID[i];
    if (SRCF32) {
      float2 v0 = *(const float2*)((const float*)hsrc + (size_t)s0 * 128 + lane * 2);
      a0 += v0.x; a1 += v0.y;
    } else {
      unsigned u0 = *(const unsigned*)((const unsigned short*)hsrc + (size_t)s0 * 128 + lane * 2);
      a0 += ffrom(u0 << 16); a1 += ffrom(u0 & 0xFFFF0000u);
    }
  }
  a0 += b0; a1 += b1;
  float inv = (end > start) ? 1.0f / (float)(end - start) : 0.0f;
  unsigned o = (unsigned)f2bf(a0 * inv) | ((unsigned)f2bf(a1 * inv) << 16);
  *(unsigned*)(meanB + (size_t)row * 128 + lane * 2) = o;
}

// GEMM: 4 waves/block, wave owns 32 rows (2x 16-row tiles).
// acc = mean@Wl + x@Wr (bf16 MFMA, fp32 accum), +bias, PReLU.
// mean loads as bf16 frags directly; x is fp32 (layer 1, converted in-reg)
// or bf16 (layers 2-3). Output bf16 rows (may alias meanB: each wave reads
// only its own rows, all reads precede epilogue stores) or fp32 (layer 3).
template <bool XF32, bool OUTF32>
__global__ __launch_bounds__(256) void gemm_kernel(
    const unsigned short* __restrict__ meanB, const void* __restrict__ xsrc,
    const unsigned short* __restrict__ W,
    const float* __restrict__ bias, const float* __restrict__ alpha,
    void* __restrict__ outp, int n) {
  const int lane = threadIdx.x & 63;
  const int wv = threadIdx.x >> 6;
  const int rbase = blockIdx.x * 128 + wv * 32;
  const int g = lane >> 4;
  const int r16 = lane & 15;

  f32x4 acc[2][8] = {};

  for (int ks = 0; ks < 4; ++ks) {
    bf16x8 am[2], ax[2];
#pragma unroll
    for (int t = 0; t < 2; ++t) {
      const int row = rbase + t * 16 + r16;
      if (row < n) {
        am[t] = *(const bf16x8*)(meanB + (size_t)row * 128 + ks * 32 + g * 8);
        if (XF32) {
          const float* xp = (const float*)xsrc + (size_t)row * 128 + ks * 32 + g * 8;
          float xv[8];
          *(float4*)&xv[0] = *(const float4*)(xp);
          *(float4*)&xv[4] = *(const float4*)(xp + 4);
          u32x4 w;
#pragma unroll
          for (int p = 0; p < 4; ++p) {
            w[p] = (unsigned)f2bf(xv[2 * p]) | ((unsigned)f2bf(xv[2 * p + 1]) << 16);
          }
          ax[t] = __builtin_bit_cast(bf16x8, w);
        } else {
          ax[t] = *(const bf16x8*)((const unsigned short*)xsrc + (size_t)row * 128 + ks * 32 + g * 8);
        }
      } else {
        am[t] = (bf16x8)0;
        ax[t] = (bf16x8)0;
      }
    }
    const unsigned short* wb = W + (size_t)ks * 4096 + (size_t)lane * 8;
#pragma unroll
    for (int cf = 0; cf < 8; ++cf) {
      const unsigned short* wp = wb + cf * 512;
      bf16x8 wl = *(const bf16x8*)(wp);
      bf16x8 wr = *(const bf16x8*)(wp + 16384);
#pragma unroll
      for (int t = 0; t < 2; ++t) {
        acc[t][cf] = __builtin_amdgcn_mfma_f32_16x16x32_bf16(am[t], wl, acc[t][cf], 0, 0, 0);
        acc[t][cf] = __builtin_amdgcn_mfma_f32_16x16x32_bf16(ax[t], wr, acc[t][cf], 0, 0, 0);
      }
    }
  }

  // Epilogue: C/D layout col = lane&15, row = (lane>>4)*4 + i (verified).
  const int ocol0 = lane & 15;
  const int orow_off = (lane >> 4) * 4;
#pragma unroll
  for (int cf = 0; cf < 8; ++cf) {
    const int ocol = cf * 16 + ocol0;
    const float b = bias[ocol];
    const float a = alpha[ocol];
#pragma unroll
    for (int t = 0; t < 2; ++t) {
      const int orb = rbase + t * 16 + orow_off;
#pragma unroll
      for (int i = 0; i < 4; ++i) {
        const int orow = orb + i;
        if (orow < n) {
          float v = acc[t][cf][i] + b;
          v = v > 0.f ? v : a * v;
          if (OUTF32) {
            ((float*)outp)[(size_t)orow * 128 + ocol] = v;
          } else {
            ((unsigned short*)outp)[(size_t)orow * 128 + ocol] = f2bf(v);
          }
        }
      }
    }
  }
}

extern "C" void kernel_launch(void* const* d_in, const int* in_sizes, int n_in,
                              void* d_out, int out_size, void* d_ws, size_t ws_size,
                              hipStream_t stream) {
  const float* x = (const float*)d_in[0];
  const void* src1 = d_in[1];
  const void* dst1 = d_in[2];
  const void* src2 = d_in[3];
  const void* dst2 = d_in[4];
  const void* src3 = d_in[5];
  const void* dst3 = d_in[6];
  const float* Wl1 = (const float*)d_in[7];
  const float* Wr1 = (const float*)d_in[8];
  const float* b1  = (const float*)d_in[9];
  const float* a1  = (const float*)d_in[10];
  const float* Wl2 = (const float*)d_in[11];
  const float* Wr2 = (const float*)d_in[12];
  const float* b2  = (const float*)d_in[13];
  const float* a2  = (const float*)d_in[14];
  const float* Wl3 = (const float*)d_in[15];
  const float* Wr3 = (const float*)d_in[16];
  const float* b3  = (const float*)d_in[17];
  const float* a3  = (const float*)d_in[18];

  // ws layout: M1 (N1*128 u16), M2 (N2*128 u16), M3 (N3*128 u16),
  //            CNT (cNT i), OFFS (cNT i), EID (cET i), bsum (1024 i),
  //            flag (64 i), wpk (3*32768 u16)
  unsigned short* M1 = (unsigned short*)d_ws;          // mean1 -> h1 (in-place)
  unsigned short* M2 = M1 + (size_t)cN1 * 128;         // mean2 -> h2 (in-place)
  unsigned short* M3 = M2 + (size_t)cN2 * 128;         // mean3
  int* CNT = (int*)(M3 + (size_t)cN3 * 128);
  int* OFFS = CNT + cNT;
  int* EID = OFFS + cNT;
  int* bsum = EID + cET;
  int* flag = bsum + 1024;
  unsigned short* wpk = (unsigned short*)(flag + 64);

  const int nb = NDIV_UP(cNT, 1024);  // 342 <= 512

  detect_idx64_kernel<<<1, 64, 0, stream>>>((const long long*)src1, cE1,
                                            (long long)cN0, flag);
  pack_w3_kernel<<<192, 256, 0, stream>>>(Wl1, Wr1, Wl2, Wr2, Wl3, Wr3, wpk);
  hipMemsetAsync(CNT, 0, (size_t)cNT * sizeof(int), stream);
  hist3_kernel<<<NDIV_UP(cET, 256), 256, 0, stream>>>(dst1, dst2, dst3, flag, CNT);
  scan_reduce<<<nb, 256, 0, stream>>>(CNT, cNT, bsum);
  scan_bsums<<<1, 256, 0, stream>>>(bsum, nb);
  scan_final<<<nb, 256, 0, stream>>>(CNT, cNT, bsum, OFFS);
  fill3_kernel<<<NDIV_UP(cET, 256), 256, 0, stream>>>(src1, dst1, src2, dst2,
                                                      src3, dst3, flag, OFFS, EID);

  // Layer 1: mean(x) -> M1 ; h1 = gemm(M1, x fp32) -> M1 (bf16, in-place)
  gather_kernel<true><<<NDIV_UP(cN1, 4), 256, 0, stream>>>(
      x, OFFS, EID, 0, M1, cN1);
  gemm_kernel<true, false><<<NDIV_UP(cN1, 128), 256, 0, stream>>>(
      M1, x, wpk, b1, a1, M1, cN1);

  // Layer 2: mean(h1) -> M2 ; h2 = gemm(M2, h1 bf16) -> M2 (bf16, in-place)
  gather_kernel<false><<<NDIV_UP(cN2, 4), 256, 0, stream>>>(
      M1, OFFS, EID, cN1, M2, cN2);
  gemm_kernel<false, false><<<NDIV_UP(cN2, 128), 256, 0, stream>>>(
      M2, M1, wpk + 32768, b2, a2, M2, cN2);

  // Layer 3: mean(h2) -> M3 ; out = gemm(M3, h2 bf16) -> d_out (fp32)
  gather_kernel<false><<<NDIV_UP(cN3, 4), 256, 0, stream>>>(
      M2, OFFS, EID, cN1 + cN2, M3, cN3);
  gemm_kernel<false, true><<<NDIV_UP(cN3, 128), 256, 0, stream>>>(
      M3, M2, wpk + 65536, b3, a3, d_out, cN3);
}

// Round 9
// 363.100 us; speedup vs baseline: 1.5102x; 1.0947x over previous
//
#include <hip/hip_runtime.h>

// GraphSAGE 3-layer encoder, bf16 feature pipeline.
// Batched CSR build (hist -> scan -> fill, concatenated dst space), then per
// layer: gather-mean (one WAVE per dst row, contiguous row reads, fp32 accum,
// bf16 row out) -> GEMM (MFMA bf16, W staged once into LDS, single barrier):
// out = mean@Wl + b + x@Wr, PReLU.

constexpr int cN0 = 400000, cN1 = 200000, cN2 = 100000, cN3 = 50000;
constexpr int cE1 = 500000, cE2 = 300000, cE3 = 150000;
constexpr int cNT = cN1 + cN2 + cN3;   // 350000 concatenated dst rows
constexpr int cET = cE1 + cE2 + cE3;   // 950000 concatenated edges

#define NDIV_UP(a, b) (((a) + (b) - 1) / (b))

typedef __attribute__((ext_vector_type(8))) short bf16x8;
typedef __attribute__((ext_vector_type(4))) float f32x4;
typedef __attribute__((ext_vector_type(4))) unsigned u32x4;

__device__ __forceinline__ unsigned fbits(float f) {
  return __builtin_bit_cast(unsigned, f);
}
__device__ __forceinline__ float ffrom(unsigned u) {
  return __builtin_bit_cast(float, u);
}
__device__ __forceinline__ unsigned short f2bf(float f) {  // round-to-nearest
  unsigned u = fbits(f);
  unsigned r = u + 0x7FFFu + ((u >> 16) & 1u);
  return (unsigned short)(r >> 16);
}

// Detect whether index buffers are int64 (JAX x64) or int32 — parallel, 1 wave.
__global__ void detect_idx64_kernel(const long long* __restrict__ p, int E,
                                    long long nmax, int* __restrict__ flag) {
  int t = threadIdx.x;
  int n = E < 512 ? E : 512;
  int bad = 0;
  for (int i = t; i < n; i += 64) {
    long long v = p[i];
    if (v < 0 || v >= nmax) bad = 1;
  }
  unsigned long long b = __ballot(bad);
  if (t == 0) *flag = (b == 0ull) ? 1 : 0;
}

__device__ __forceinline__ int load_idx(const void* p, int i, int flag) {
  return flag ? (int)((const long long*)p)[i] : ((const int*)p)[i];
}

// Histogram over concatenated dst space.
__global__ void hist3_kernel(const void* __restrict__ d1, const void* __restrict__ d2,
                             const void* __restrict__ d3, const int* __restrict__ flag,
                             int* __restrict__ CNT) {
  int e = blockIdx.x * 256 + threadIdx.x;
  if (e >= cET) return;
  int f = *flag;
  int d;
  if (e < cE1) d = load_idx(d1, e, f);
  else if (e < cE1 + cE2) d = cN1 + load_idx(d2, e - cE1, f);
  else d = cN1 + cN2 + load_idx(d3, e - cE1 - cE2, f);
  atomicAdd(&CNT[d], 1);
}

// ---- exclusive scan over CNT[cNT] -> OFFS[cNT], 1024 items / block ----
__global__ __launch_bounds__(256) void scan_reduce(const int* __restrict__ cnt,
                                                   int n, int* __restrict__ bsum) {
  __shared__ int s[256];
  int t = threadIdx.x;
  int base = blockIdx.x * 1024 + t * 4;
  int v = 0;
  if (base + 3 < n) {
    int4 c = *(const int4*)(cnt + base);
    v = c.x + c.y + c.z + c.w;
  } else {
    for (int i = 0; i < 4; ++i)
      if (base + i < n) v += cnt[base + i];
  }
  s[t] = v;
  __syncthreads();
  for (int off = 128; off > 0; off >>= 1) {
    if (t < off) s[t] += s[t + off];
    __syncthreads();
  }
  if (t == 0) bsum[blockIdx.x] = s[0];
}

// Parallel single-block exclusive scan over up to 512 block-sums.
__global__ __launch_bounds__(256) void scan_bsums(int* __restrict__ bsum, int nb) {
  __shared__ int s[256];
  int t = threadIdx.x;
  int v0 = (2 * t < nb) ? bsum[2 * t] : 0;
  int v1 = (2 * t + 1 < nb) ? bsum[2 * t + 1] : 0;
  int p = v0 + v1;
  s[t] = p;
  __syncthreads();
  for (int off = 1; off < 256; off <<= 1) {
    int x = (t >= off) ? s[t - off] : 0;
    __syncthreads();
    s[t] += x;
    __syncthreads();
  }
  int excl = s[t] - p;
  if (2 * t < nb) bsum[2 * t] = excl;
  if (2 * t + 1 < nb) bsum[2 * t + 1] = excl + v0;
}

__global__ __launch_bounds__(256) void scan_final(const int* __restrict__ cnt,
                                                  int n, const int* __restrict__ bsum,
                                                  int* __restrict__ offs) {
  __shared__ int s[256];
  int t = threadIdx.x;
  int base = blockIdx.x * 1024 + t * 4;
  int v0 = 0, v1 = 0, v2 = 0, v3 = 0;
  if (base + 3 < n) {
    int4 c = *(const int4*)(cnt + base);
    v0 = c.x; v1 = c.y; v2 = c.z; v3 = c.w;
  } else {
    if (base + 0 < n) v0 = cnt[base + 0];
    if (base + 1 < n) v1 = cnt[base + 1];
    if (base + 2 < n) v2 = cnt[base + 2];
  }
  int tsum = v0 + v1 + v2 + v3;
  s[t] = tsum;
  __syncthreads();
  for (int off = 1; off < 256; off <<= 1) {
    int x = (t >= off) ? s[t - off] : 0;
    __syncthreads();
    s[t] += x;
    __syncthreads();
  }
  int excl = s[t] - tsum;
  int o = bsum[blockIdx.x] + excl;
  if (base + 0 < n) offs[base + 0] = o;
  o += v0;
  if (base + 1 < n) offs[base + 1] = o;
  o += v1;
  if (base + 2 < n) offs[base + 2] = o;
  o += v2;
  if (base + 3 < n) offs[base + 3] = o;
}

// Bucket-fill into concatenated EID; post-fill OFFS[d] == pre-fill OFFS[d+1].
__global__ void fill3_kernel(const void* __restrict__ s1, const void* __restrict__ d1,
                             const void* __restrict__ s2, const void* __restrict__ d2,
                             const void* __restrict__ s3, const void* __restrict__ d3,
                             const int* __restrict__ flag,
                             int* __restrict__ OFFS, int* __restrict__ EID) {
  int e = blockIdx.x * 256 + threadIdx.x;
  if (e >= cET) return;
  int f = *flag;
  int s, d;
  if (e < cE1) {
    s = load_idx(s1, e, f);
    d = load_idx(d1, e, f);
  } else if (e < cE1 + cE2) {
    int i = e - cE1;
    s = load_idx(s2, i, f);
    d = cN1 + load_idx(d2, i, f);
  } else {
    int i = e - cE1 - cE2;
    s = load_idx(s3, i, f);
    d = cN1 + cN2 + load_idx(d3, i, f);
  }
  int pos = atomicAdd(&OFFS[d], 1);
  EID[pos] = s;
}

// Pre-pack weights (all 3 layers) into per-lane MFMA B-fragment order, RTN
// bf16. Per layer: Wl|Wr x16384 u16 (64 KB).
// r = ks*4096 + cf*512 + l*8 + j ; k = ks*32+(l>>4)*8+j ; col = cf*16+(l&15).
__global__ void pack_w3_kernel(const float* __restrict__ Wl1, const float* __restrict__ Wr1,
                               const float* __restrict__ Wl2, const float* __restrict__ Wr2,
                               const float* __restrict__ Wl3, const float* __restrict__ Wr3,
                               unsigned short* __restrict__ wpk) {
  int idx = blockIdx.x * 256 + threadIdx.x;
  if (idx >= 3 * 16384) return;
  int L = idx >> 14;
  int r = idx & 16383;
  const float* Wl = L == 0 ? Wl1 : (L == 1 ? Wl2 : Wl3);
  const float* Wr = L == 0 ? Wr1 : (L == 1 ? Wr2 : Wr3);
  unsigned short* o = wpk + L * 32768;
  int j = r & 7, l = (r >> 3) & 63, cf = (r >> 9) & 7, ks = r >> 12;
  int k = ks * 32 + (l >> 4) * 8 + j;
  int col = cf * 16 + (l & 15);
  o[r] = f2bf(Wl[k * 128 + col]);
  o[16384 + r] = f2bf(Wr[k * 128 + col]);
}

// Gather-mean: ONE WAVE per dst row. Lane owns cols 2l,2l+1. Each edge is a
// fully contiguous row read (512B fp32 / 256B bf16 per instruction). fp32
// accumulate, mean, RTN-bf16 row out (256B contiguous).
template <bool SRCF32>
__global__ __launch_bounds__(256) void gather_kernel(
    const void* __restrict__ hsrc, const int* __restrict__ OFFS,
    const int* __restrict__ EID, int rowoff,
    unsigned short* __restrict__ meanB, int n) {
  int row = blockIdx.x * 4 + (threadIdx.x >> 6);
  if (row >= n) return;
  int lane = threadIdx.x & 63;
  int gr = rowoff + row;
  int start = gr ? OFFS[gr - 1] : 0;
  int end = OFFS[gr];
  float a0 = 0.f, a1 = 0.f, b0 = 0.f, b1 = 0.f;
  int i = start;
  for (; i + 1 < end; i += 2) {
    int s0 = EID[i], s1 = EID[i + 1];
    if (SRCF32) {
      float2 v0 = *(const float2*)((const float*)hsrc + (size_t)s0 * 128 + lane * 2);
      float2 v1 = *(const float2*)((const float*)hsrc + (size_t)s1 * 128 + lane * 2);
      a0 += v0.x; a1 += v0.y;
      b0 += v1.x; b1 += v1.y;
    } else {
      unsigned u0 = *(const unsigned*)((const unsigned short*)hsrc + (size_t)s0 * 128 + lane * 2);
      unsigned u1 = *(const unsigned*)((const unsigned short*)hsrc + (size_t)s1 * 128 + lane * 2);
      a0 += ffrom(u0 << 16); a1 += ffrom(u0 & 0xFFFF0000u);
      b0 += ffrom(u1 << 16); b1 += ffrom(u1 & 0xFFFF0000u);
    }
  }
  if (i < end) {
    int s0 = EID[i];
    if (SRCF32) {
      float2 v0 = *(const float2*)((const float*)hsrc + (size_t)s0 * 128 + lane * 2);
      a0 += v0.x; a1 += v0.y;
    } else {
      unsigned u0 = *(const unsigned*)((const unsigned short*)hsrc + (size_t)s0 * 128 + lane * 2);
      a0 += ffrom(u0 << 16); a1 += ffrom(u0 & 0xFFFF0000u);
    }
  }
  a0 += b0; a1 += b1;
  float inv = (end > start) ? 1.0f / (float)(end - start) : 0.0f;
  unsigned o = (unsigned)f2bf(a0 * inv) | ((unsigned)f2bf(a1 * inv) << 16);
  *(unsigned*)(meanB + (size_t)row * 128 + lane * 2) = o;
}

// GEMM: 4 waves/block, wave owns 32 rows (2x 16-row tiles).
// Phase 1: issue ALL A-loads (mean bf16 + x) into registers.
// Phase 2: stage the layer's full packed W (64 KB) into LDS (once).
// Phase 3: one barrier; ks/cf loop reads B via conflict-free ds_read_b128,
//          4 MFMA per (ks,cf); no further barriers or global B traffic.
// acc = mean@Wl + x@Wr, +bias, PReLU. Output may alias meanB: every read
// (A hoisted up front) precedes every epilogue store.
template <bool XF32, bool OUTF32>
__global__ __launch_bounds__(256, 2) void gemm_kernel(
    const unsigned short* __restrict__ meanB, const void* __restrict__ xsrc,
    const unsigned short* __restrict__ W,
    const float* __restrict__ bias, const float* __restrict__ alpha,
    void* __restrict__ outp, int n) {
  __shared__ __align__(16) unsigned short wlds[32768];  // 64 KB: full layer W
  const int tid = threadIdx.x;
  const int lane = tid & 63;
  const int wv = tid >> 6;
  const int rbase = blockIdx.x * 128 + wv * 32;
  const int g = lane >> 4;
  const int r16 = lane & 15;

  // Phase 1: all A loads issued first (latency hides under W staging).
  bf16x8 am[2][4], ax[2][4];
  float4 xr[2][4][2];
#pragma unroll
  for (int t = 0; t < 2; ++t) {
    const int row = rbase + t * 16 + r16;
    const bool ok = row < n;
#pragma unroll
    for (int ks = 0; ks < 4; ++ks) {
      if (ok) {
        am[t][ks] = *(const bf16x8*)(meanB + (size_t)row * 128 + ks * 32 + g * 8);
        if (XF32) {
          const float* xp = (const float*)xsrc + (size_t)row * 128 + ks * 32 + g * 8;
          xr[t][ks][0] = *(const float4*)(xp);
          xr[t][ks][1] = *(const float4*)(xp + 4);
        } else {
          ax[t][ks] = *(const bf16x8*)((const unsigned short*)xsrc +
                                       (size_t)row * 128 + ks * 32 + g * 8);
        }
      } else {
        am[t][ks] = (bf16x8)0;
        if (XF32) {
          xr[t][ks][0] = make_float4(0.f, 0.f, 0.f, 0.f);
          xr[t][ks][1] = make_float4(0.f, 0.f, 0.f, 0.f);
        } else {
          ax[t][ks] = (bf16x8)0;
        }
      }
    }
  }

  // Phase 2: stage W -> LDS (4096 float4, 256 threads x 16 iters).
  {
    const float4* Wg = (const float4*)W;
    float4* Ws = (float4*)wlds;
#pragma unroll
    for (int i = 0; i < 16; ++i)
      Ws[i * 256 + tid] = Wg[i * 256 + tid];
  }
  __syncthreads();

  if (XF32) {
#pragma unroll
    for (int t = 0; t < 2; ++t)
#pragma unroll
      for (int ks = 0; ks < 4; ++ks) {
        const float* xv = (const float*)&xr[t][ks][0];
        u32x4 w;
#pragma unroll
        for (int p = 0; p < 4; ++p)
          w[p] = (unsigned)f2bf(xv[2 * p]) | ((unsigned)f2bf(xv[2 * p + 1]) << 16);
        ax[t][ks] = __builtin_bit_cast(bf16x8, w);
      }
  }

  // Phase 3: MFMA loop, B from LDS.
  f32x4 acc[2][8] = {};
#pragma unroll
  for (int ks = 0; ks < 4; ++ks) {
    const unsigned short* wb = wlds + ks * 4096 + lane * 8;
#pragma unroll
    for (int cf = 0; cf < 8; ++cf) {
      const unsigned short* wp = wb + cf * 512;
      bf16x8 wl = *(const bf16x8*)(wp);
      bf16x8 wr = *(const bf16x8*)(wp + 16384);
#pragma unroll
      for (int t = 0; t < 2; ++t) {
        acc[t][cf] = __builtin_amdgcn_mfma_f32_16x16x32_bf16(am[t][ks], wl, acc[t][cf], 0, 0, 0);
        acc[t][cf] = __builtin_amdgcn_mfma_f32_16x16x32_bf16(ax[t][ks], wr, acc[t][cf], 0, 0, 0);
      }
    }
  }

  // Epilogue: C/D layout col = lane&15, row = (lane>>4)*4 + i (verified).
  const int ocol0 = lane & 15;
  const int orow_off = (lane >> 4) * 4;
#pragma unroll
  for (int cf = 0; cf < 8; ++cf) {
    const int ocol = cf * 16 + ocol0;
    const float b = bias[ocol];
    const float a = alpha[ocol];
#pragma unroll
    for (int t = 0; t < 2; ++t) {
      const int orb = rbase + t * 16 + orow_off;
#pragma unroll
      for (int i = 0; i < 4; ++i) {
        const int orow = orb + i;
        if (orow < n) {
          float v = acc[t][cf][i] + b;
          v = v > 0.f ? v : a * v;
          if (OUTF32) {
            ((float*)outp)[(size_t)orow * 128 + ocol] = v;
          } else {
            ((unsigned short*)outp)[(size_t)orow * 128 + ocol] = f2bf(v);
          }
        }
      }
    }
  }
}

extern "C" void kernel_launch(void* const* d_in, const int* in_sizes, int n_in,
                              void* d_out, int out_size, void* d_ws, size_t ws_size,
                              hipStream_t stream) {
  const float* x = (const float*)d_in[0];
  const void* src1 = d_in[1];
  const void* dst1 = d_in[2];
  const void* src2 = d_in[3];
  const void* dst2 = d_in[4];
  const void* src3 = d_in[5];
  const void* dst3 = d_in[6];
  const float* Wl1 = (const float*)d_in[7];
  const float* Wr1 = (const float*)d_in[8];
  const float* b1  = (const float*)d_in[9];
  const float* a1  = (const float*)d_in[10];
  const float* Wl2 = (const float*)d_in[11];
  const float* Wr2 = (const float*)d_in[12];
  const float* b2  = (const float*)d_in[13];
  const float* a2  = (const float*)d_in[14];
  const float* Wl3 = (const float*)d_in[15];
  const float* Wr3 = (const float*)d_in[16];
  const float* b3  = (const float*)d_in[17];
  const float* a3  = (const float*)d_in[18];

  // ws layout: M1 (N1*128 u16), M2 (N2*128 u16), M3 (N3*128 u16),
  //            CNT (cNT i), OFFS (cNT i), EID (cET i), bsum (1024 i),
  //            flag (64 i), wpk (3*32768 u16)
  unsigned short* M1 = (unsigned short*)d_ws;          // mean1 -> h1 (in-place)
  unsigned short* M2 = M1 + (size_t)cN1 * 128;         // mean2 -> h2 (in-place)
  unsigned short* M3 = M2 + (size_t)cN2 * 128;         // mean3
  int* CNT = (int*)(M3 + (size_t)cN3 * 128);
  int* OFFS = CNT + cNT;
  int* EID = OFFS + cNT;
  int* bsum = EID + cET;
  int* flag = bsum + 1024;
  unsigned short* wpk = (unsigned short*)(flag + 64);

  const int nb = NDIV_UP(cNT, 1024);  // 342 <= 512

  detect_idx64_kernel<<<1, 64, 0, stream>>>((const long long*)src1, cE1,
                                            (long long)cN0, flag);
  pack_w3_kernel<<<192, 256, 0, stream>>>(Wl1, Wr1, Wl2, Wr2, Wl3, Wr3, wpk);
  hipMemsetAsync(CNT, 0, (size_t)cNT * sizeof(int), stream);
  hist3_kernel<<<NDIV_UP(cET, 256), 256, 0, stream>>>(dst1, dst2, dst3, flag, CNT);
  scan_reduce<<<nb, 256, 0, stream>>>(CNT, cNT, bsum);
  scan_bsums<<<1, 256, 0, stream>>>(bsum, nb);
  scan_final<<<nb, 256, 0, stream>>>(CNT, cNT, bsum, OFFS);
  fill3_kernel<<<NDIV_UP(cET, 256), 256, 0, stream>>>(src1, dst1, src2, dst2,
                                                      src3, dst3, flag, OFFS, EID);

  // Layer 1: mean(x) -> M1 ; h1 = gemm(M1, x fp32) -> M1 (bf16, in-place)
  gather_kernel<true><<<NDIV_UP(cN1, 4), 256, 0, stream>>>(
      x, OFFS, EID, 0, M1, cN1);
  gemm_kernel<true, false><<<NDIV_UP(cN1, 128), 256, 0, stream>>>(
      M1, x, wpk, b1, a1, M1, cN1);

  // Layer 2: mean(h1) -> M2 ; h2 = gemm(M2, h1 bf16) -> M2 (bf16, in-place)
  gather_kernel<false><<<NDIV_UP(cN2, 4), 256, 0, stream>>>(
      M1, OFFS, EID, cN1, M2, cN2);
  gemm_kernel<false, false><<<NDIV_UP(cN2, 128), 256, 0, stream>>>(
      M2, M1, wpk + 32768, b2, a2, M2, cN2);

  // Layer 3: mean(h2) -> M3 ; out = gemm(M3, h2 bf16) -> d_out (fp32)
  gather_kernel<false><<<NDIV_UP(cN3, 4), 256, 0, stream>>>(
      M2, OFFS, EID, cN1 + cN2, M3, cN3);
  gemm_kernel<false, true><<<NDIV_UP(cN3, 128), 256, 0, stream>>>(
      M3, M2, wpk + 65536, b3, a3, d_out, cN3);
}

// Round 10
// 355.076 us; speedup vs baseline: 1.5443x; 1.0226x over previous
//
#include <hip/hip_runtime.h>

// GraphSAGE 3-layer encoder, bf16 feature pipeline.
// Batched CSR build (hist -> scan -> fill, concatenated dst space), then per
// layer: gather-mean (one wave per dst row, EDGE-PAIRED full-row loads: wave
// halves read two edges' rows per instruction, fp32 accum, shfl-combine,
// bf16 row out) -> GEMM (MFMA bf16, W staged once into LDS, single barrier):
// out = mean@Wl + b + x@Wr, PReLU.

constexpr int cN0 = 400000, cN1 = 200000, cN2 = 100000, cN3 = 50000;
constexpr int cE1 = 500000, cE2 = 300000, cE3 = 150000;
constexpr int cNT = cN1 + cN2 + cN3;   // 350000 concatenated dst rows
constexpr int cET = cE1 + cE2 + cE3;   // 950000 concatenated edges

#define NDIV_UP(a, b) (((a) + (b) - 1) / (b))

typedef __attribute__((ext_vector_type(8))) short bf16x8;
typedef __attribute__((ext_vector_type(4))) float f32x4;
typedef __attribute__((ext_vector_type(4))) unsigned u32x4;

__device__ __forceinline__ unsigned fbits(float f) {
  return __builtin_bit_cast(unsigned, f);
}
__device__ __forceinline__ float ffrom(unsigned u) {
  return __builtin_bit_cast(float, u);
}
__device__ __forceinline__ unsigned short f2bf(float f) {  // round-to-nearest
  unsigned u = fbits(f);
  unsigned r = u + 0x7FFFu + ((u >> 16) & 1u);
  return (unsigned short)(r >> 16);
}

// Detect whether index buffers are int64 (JAX x64) or int32 — parallel, 1 wave.
__global__ void detect_idx64_kernel(const long long* __restrict__ p, int E,
                                    long long nmax, int* __restrict__ flag) {
  int t = threadIdx.x;
  int n = E < 512 ? E : 512;
  int bad = 0;
  for (int i = t; i < n; i += 64) {
    long long v = p[i];
    if (v < 0 || v >= nmax) bad = 1;
  }
  unsigned long long b = __ballot(bad);
  if (t == 0) *flag = (b == 0ull) ? 1 : 0;
}

__device__ __forceinline__ int load_idx(const void* p, int i, int flag) {
  return flag ? (int)((const long long*)p)[i] : ((const int*)p)[i];
}

// Histogram over concatenated dst space.
__global__ void hist3_kernel(const void* __restrict__ d1, const void* __restrict__ d2,
                             const void* __restrict__ d3, const int* __restrict__ flag,
                             int* __restrict__ CNT) {
  int e = blockIdx.x * 256 + threadIdx.x;
  if (e >= cET) return;
  int f = *flag;
  int d;
  if (e < cE1) d = load_idx(d1, e, f);
  else if (e < cE1 + cE2) d = cN1 + load_idx(d2, e - cE1, f);
  else d = cN1 + cN2 + load_idx(d3, e - cE1 - cE2, f);
  atomicAdd(&CNT[d], 1);
}

// ---- exclusive scan over CNT[cNT] -> OFFS[cNT], 1024 items / block ----
__global__ __launch_bounds__(256) void scan_reduce(const int* __restrict__ cnt,
                                                   int n, int* __restrict__ bsum) {
  __shared__ int s[256];
  int t = threadIdx.x;
  int base = blockIdx.x * 1024 + t * 4;
  int v = 0;
  if (base + 3 < n) {
    int4 c = *(const int4*)(cnt + base);
    v = c.x + c.y + c.z + c.w;
  } else {
    for (int i = 0; i < 4; ++i)
      if (base + i < n) v += cnt[base + i];
  }
  s[t] = v;
  __syncthreads();
  for (int off = 128; off > 0; off >>= 1) {
    if (t < off) s[t] += s[t + off];
    __syncthreads();
  }
  if (t == 0) bsum[blockIdx.x] = s[0];
}

// Parallel single-block exclusive scan over up to 512 block-sums.
__global__ __launch_bounds__(256) void scan_bsums(int* __restrict__ bsum, int nb) {
  __shared__ int s[256];
  int t = threadIdx.x;
  int v0 = (2 * t < nb) ? bsum[2 * t] : 0;
  int v1 = (2 * t + 1 < nb) ? bsum[2 * t + 1] : 0;
  int p = v0 + v1;
  s[t] = p;
  __syncthreads();
  for (int off = 1; off < 256; off <<= 1) {
    int x = (t >= off) ? s[t - off] : 0;
    __syncthreads();
    s[t] += x;
    __syncthreads();
  }
  int excl = s[t] - p;
  if (2 * t < nb) bsum[2 * t] = excl;
  if (2 * t + 1 < nb) bsum[2 * t + 1] = excl + v0;
}

__global__ __launch_bounds__(256) void scan_final(const int* __restrict__ cnt,
                                                  int n, const int* __restrict__ bsum,
                                                  int* __restrict__ offs) {
  __shared__ int s[256];
  int t = threadIdx.x;
  int base = blockIdx.x * 1024 + t * 4;
  int v0 = 0, v1 = 0, v2 = 0, v3 = 0;
  if (base + 3 < n) {
    int4 c = *(const int4*)(cnt + base);
    v0 = c.x; v1 = c.y; v2 = c.z; v3 = c.w;
  } else {
    if (base + 0 < n) v0 = cnt[base + 0];
    if (base + 1 < n) v1 = cnt[base + 1];
    if (base + 2 < n) v2 = cnt[base + 2];
  }
  int tsum = v0 + v1 + v2 + v3;
  s[t] = tsum;
  __syncthreads();
  for (int off = 1; off < 256; off <<= 1) {
    int x = (t >= off) ? s[t - off] : 0;
    __syncthreads();
    s[t] += x;
    __syncthreads();
  }
  int excl = s[t] - tsum;
  int o = bsum[blockIdx.x] + excl;
  if (base + 0 < n) offs[base + 0] = o;
  o += v0;
  if (base + 1 < n) offs[base + 1] = o;
  o += v1;
  if (base + 2 < n) offs[base + 2] = o;
  o += v2;
  if (base + 3 < n) offs[base + 3] = o;
}

// Bucket-fill into concatenated EID; post-fill OFFS[d] == pre-fill OFFS[d+1].
__global__ void fill3_kernel(const void* __restrict__ s1, const void* __restrict__ d1,
                             const void* __restrict__ s2, const void* __restrict__ d2,
                             const void* __restrict__ s3, const void* __restrict__ d3,
                             const int* __restrict__ flag,
                             int* __restrict__ OFFS, int* __restrict__ EID) {
  int e = blockIdx.x * 256 + threadIdx.x;
  if (e >= cET) return;
  int f = *flag;
  int s, d;
  if (e < cE1) {
    s = load_idx(s1, e, f);
    d = load_idx(d1, e, f);
  } else if (e < cE1 + cE2) {
    int i = e - cE1;
    s = load_idx(s2, i, f);
    d = cN1 + load_idx(d2, i, f);
  } else {
    int i = e - cE1 - cE2;
    s = load_idx(s3, i, f);
    d = cN1 + cN2 + load_idx(d3, i, f);
  }
  int pos = atomicAdd(&OFFS[d], 1);
  EID[pos] = s;
}

// Pre-pack weights (all 3 layers) into per-lane MFMA B-fragment order, RTN
// bf16. Per layer: Wl|Wr x16384 u16 (64 KB).
// r = ks*4096 + cf*512 + l*8 + j ; k = ks*32+(l>>4)*8+j ; col = cf*16+(l&15).
__global__ void pack_w3_kernel(const float* __restrict__ Wl1, const float* __restrict__ Wr1,
                               const float* __restrict__ Wl2, const float* __restrict__ Wr2,
                               const float* __restrict__ Wl3, const float* __restrict__ Wr3,
                               unsigned short* __restrict__ wpk) {
  int idx = blockIdx.x * 256 + threadIdx.x;
  if (idx >= 3 * 16384) return;
  int L = idx >> 14;
  int r = idx & 16383;
  const float* Wl = L == 0 ? Wl1 : (L == 1 ? Wl2 : Wl3);
  const float* Wr = L == 0 ? Wr1 : (L == 1 ? Wr2 : Wr3);
  unsigned short* o = wpk + L * 32768;
  int j = r & 7, l = (r >> 3) & 63, cf = (r >> 9) & 7, ks = r >> 12;
  int k = ks * 32 + (l >> 4) * 8 + j;
  int col = cf * 16 + (l & 15);
  o[r] = f2bf(Wl[k * 128 + col]);
  o[16384 + r] = f2bf(Wr[k * 128 + col]);
}

// Gather-mean: ONE WAVE per dst row, EDGE-PAIRED loads.
// Wave halves: lanes 0-31 read edge i's row, lanes 32-63 read edge i+1's row;
// lane q=lane&31 covers cols 4q..4q+3 (float4 / bf16x4). One instruction thus
// fetches TWO full rows (1024B fp32 / 512B bf16). 2 pairs unrolled -> 4 rows
// in flight. Halves combined via __shfl_xor(32); lanes 0-31 write the 256B
// bf16 mean row.
template <bool SRCF32>
__global__ __launch_bounds__(256) void gather_kernel(
    const void* __restrict__ hsrc, const int* __restrict__ OFFS,
    const int* __restrict__ EID, int rowoff,
    unsigned short* __restrict__ meanB, int n) {
  int row = blockIdx.x * 4 + (threadIdx.x >> 6);
  if (row >= n) return;
  const int lane = threadIdx.x & 63;
  const int half = lane >> 5;
  const int q = lane & 31;
  int gr = rowoff + row;
  int start = gr ? OFFS[gr - 1] : 0;
  int end = OFFS[gr];

  float a0 = 0.f, a1 = 0.f, a2 = 0.f, a3 = 0.f;
  float b0 = 0.f, b1 = 0.f, b2 = 0.f, b3 = 0.f;

#define ACC_ROW(s, c0, c1, c2, c3)                                             \
  do {                                                                         \
    if (SRCF32) {                                                              \
      const float4 v = *(const float4*)((const float*)hsrc +                   \
                                        (size_t)(s) * 128 + q * 4);            \
      c0 += v.x; c1 += v.y; c2 += v.z; c3 += v.w;                              \
    } else {                                                                   \
      const uint2 u = *(const uint2*)((const unsigned short*)hsrc +            \
                                      (size_t)(s) * 128 + q * 4);              \
      c0 += ffrom(u.x << 16); c1 += ffrom(u.x & 0xFFFF0000u);                  \
      c2 += ffrom(u.y << 16); c3 += ffrom(u.y & 0xFFFF0000u);                  \
    }                                                                          \
  } while (0)

  int i = start;
  for (; i + 3 < end; i += 4) {
    int sA = EID[i + half];
    int sB = EID[i + 2 + half];
    ACC_ROW(sA, a0, a1, a2, a3);
    ACC_ROW(sB, b0, b1, b2, b3);
  }
  if (i + 1 < end) {
    int sA = EID[i + half];
    ACC_ROW(sA, a0, a1, a2, a3);
    i += 2;
  }
  if (i < end && half == 0) {
    int s = EID[i];
    ACC_ROW(s, b0, b1, b2, b3);
  }
#undef ACC_ROW

  a0 += b0; a1 += b1; a2 += b2; a3 += b3;
  a0 += __shfl_xor(a0, 32);
  a1 += __shfl_xor(a1, 32);
  a2 += __shfl_xor(a2, 32);
  a3 += __shfl_xor(a3, 32);

  if (half == 0) {
    const float inv = (end > start) ? 1.0f / (float)(end - start) : 0.0f;
    uint2 o;
    o.x = (unsigned)f2bf(a0 * inv) | ((unsigned)f2bf(a1 * inv) << 16);
    o.y = (unsigned)f2bf(a2 * inv) | ((unsigned)f2bf(a3 * inv) << 16);
    *(uint2*)(meanB + (size_t)row * 128 + q * 4) = o;
  }
}

// GEMM: 4 waves/block, wave owns 32 rows (2x 16-row tiles).
// Phase 1: issue ALL A-loads (mean bf16 + x) into registers.
// Phase 2: stage the layer's full packed W (64 KB) into LDS (once).
// Phase 3: one barrier; ks/cf loop reads B via conflict-free ds_read_b128,
//          4 MFMA per (ks,cf); no further barriers or global B traffic.
// acc = mean@Wl + x@Wr, +bias, PReLU. Output may alias meanB: every read
// (A hoisted up front) precedes every epilogue store.
template <bool XF32, bool OUTF32>
__global__ __launch_bounds__(256, 2) void gemm_kernel(
    const unsigned short* __restrict__ meanB, const void* __restrict__ xsrc,
    const unsigned short* __restrict__ W,
    const float* __restrict__ bias, const float* __restrict__ alpha,
    void* __restrict__ outp, int n) {
  __shared__ __align__(16) unsigned short wlds[32768];  // 64 KB: full layer W
  const int tid = threadIdx.x;
  const int lane = tid & 63;
  const int wv = tid >> 6;
  const int rbase = blockIdx.x * 128 + wv * 32;
  const int g = lane >> 4;
  const int r16 = lane & 15;

  // Phase 1: all A loads issued first (latency hides under W staging).
  bf16x8 am[2][4], ax[2][4];
  float4 xr[2][4][2];
#pragma unroll
  for (int t = 0; t < 2; ++t) {
    const int row = rbase + t * 16 + r16;
    const bool ok = row < n;
#pragma unroll
    for (int ks = 0; ks < 4; ++ks) {
      if (ok) {
        am[t][ks] = *(const bf16x8*)(meanB + (size_t)row * 128 + ks * 32 + g * 8);
        if (XF32) {
          const float* xp = (const float*)xsrc + (size_t)row * 128 + ks * 32 + g * 8;
          xr[t][ks][0] = *(const float4*)(xp);
          xr[t][ks][1] = *(const float4*)(xp + 4);
        } else {
          ax[t][ks] = *(const bf16x8*)((const unsigned short*)xsrc +
                                       (size_t)row * 128 + ks * 32 + g * 8);
        }
      } else {
        am[t][ks] = (bf16x8)0;
        if (XF32) {
          xr[t][ks][0] = make_float4(0.f, 0.f, 0.f, 0.f);
          xr[t][ks][1] = make_float4(0.f, 0.f, 0.f, 0.f);
        } else {
          ax[t][ks] = (bf16x8)0;
        }
      }
    }
  }

  // Phase 2: stage W -> LDS (4096 float4, 256 threads x 16 iters).
  {
    const float4* Wg = (const float4*)W;
    float4* Ws = (float4*)wlds;
#pragma unroll
    for (int i = 0; i < 16; ++i)
      Ws[i * 256 + tid] = Wg[i * 256 + tid];
  }
  __syncthreads();

  if (XF32) {
#pragma unroll
    for (int t = 0; t < 2; ++t)
#pragma unroll
      for (int ks = 0; ks < 4; ++ks) {
        const float* xv = (const float*)&xr[t][ks][0];
        u32x4 w;
#pragma unroll
        for (int p = 0; p < 4; ++p)
          w[p] = (unsigned)f2bf(xv[2 * p]) | ((unsigned)f2bf(xv[2 * p + 1]) << 16);
        ax[t][ks] = __builtin_bit_cast(bf16x8, w);
      }
  }

  // Phase 3: MFMA loop, B from LDS.
  f32x4 acc[2][8] = {};
#pragma unroll
  for (int ks = 0; ks < 4; ++ks) {
    const unsigned short* wb = wlds + ks * 4096 + lane * 8;
#pragma unroll
    for (int cf = 0; cf < 8; ++cf) {
      const unsigned short* wp = wb + cf * 512;
      bf16x8 wl = *(const bf16x8*)(wp);
      bf16x8 wr = *(const bf16x8*)(wp + 16384);
#pragma unroll
      for (int t = 0; t < 2; ++t) {
        acc[t][cf] = __builtin_amdgcn_mfma_f32_16x16x32_bf16(am[t][ks], wl, acc[t][cf], 0, 0, 0);
        acc[t][cf] = __builtin_amdgcn_mfma_f32_16x16x32_bf16(ax[t][ks], wr, acc[t][cf], 0, 0, 0);
      }
    }
  }

  // Epilogue: C/D layout col = lane&15, row = (lane>>4)*4 + i (verified).
  const int ocol0 = lane & 15;
  const int orow_off = (lane >> 4) * 4;
#pragma unroll
  for (int cf = 0; cf < 8; ++cf) {
    const int ocol = cf * 16 + ocol0;
    const float b = bias[ocol];
    const float a = alpha[ocol];
#pragma unroll
    for (int t = 0; t < 2; ++t) {
      const int orb = rbase + t * 16 + orow_off;
#pragma unroll
      for (int i = 0; i < 4; ++i) {
        const int orow = orb + i;
        if (orow < n) {
          float v = acc[t][cf][i] + b;
          v = v > 0.f ? v : a * v;
          if (OUTF32) {
            ((float*)outp)[(size_t)orow * 128 + ocol] = v;
          } else {
            ((unsigned short*)outp)[(size_t)orow * 128 + ocol] = f2bf(v);
          }
        }
      }
    }
  }
}

extern "C" void kernel_launch(void* const* d_in, const int* in_sizes, int n_in,
                              void* d_out, int out_size, void* d_ws, size_t ws_size,
                              hipStream_t stream) {
  const float* x = (const float*)d_in[0];
  const void* src1 = d_in[1];
  const void* dst1 = d_in[2];
  const void* src2 = d_in[3];
  const void* dst2 = d_in[4];
  const void* src3 = d_in[5];
  const void* dst3 = d_in[6];
  const float* Wl1 = (const float*)d_in[7];
  const float* Wr1 = (const float*)d_in[8];
  const float* b1  = (const float*)d_in[9];
  const float* a1  = (const float*)d_in[10];
  const float* Wl2 = (const float*)d_in[11];
  const float* Wr2 = (const float*)d_in[12];
  const float* b2  = (const float*)d_in[13];
  const float* a2  = (const float*)d_in[14];
  const float* Wl3 = (const float*)d_in[15];
  const float* Wr3 = (const float*)d_in[16];
  const float* b3  = (const float*)d_in[17];
  const float* a3  = (const float*)d_in[18];

  // ws layout: M1 (N1*128 u16), M2 (N2*128 u16), M3 (N3*128 u16),
  //            CNT (cNT i), OFFS (cNT i), EID (cET i), bsum (1024 i),
  //            flag (64 i), wpk (3*32768 u16)
  unsigned short* M1 = (unsigned short*)d_ws;          // mean1 -> h1 (in-place)
  unsigned short* M2 = M1 + (size_t)cN1 * 128;         // mean2 -> h2 (in-place)
  unsigned short* M3 = M2 + (size_t)cN2 * 128;         // mean3
  int* CNT = (int*)(M3 + (size_t)cN3 * 128);
  int* OFFS = CNT + cNT;
  int* EID = OFFS + cNT;
  int* bsum = EID + cET;
  int* flag = bsum + 1024;
  unsigned short* wpk = (unsigned short*)(flag + 64);

  const int nb = NDIV_UP(cNT, 1024);  // 342 <= 512

  detect_idx64_kernel<<<1, 64, 0, stream>>>((const long long*)src1, cE1,
                                            (long long)cN0, flag);
  pack_w3_kernel<<<192, 256, 0, stream>>>(Wl1, Wr1, Wl2, Wr2, Wl3, Wr3, wpk);
  hipMemsetAsync(CNT, 0, (size_t)cNT * sizeof(int), stream);
  hist3_kernel<<<NDIV_UP(cET, 256), 256, 0, stream>>>(dst1, dst2, dst3, flag, CNT);
  scan_reduce<<<nb, 256, 0, stream>>>(CNT, cNT, bsum);
  scan_bsums<<<1, 256, 0, stream>>>(bsum, nb);
  scan_final<<<nb, 256, 0, stream>>>(CNT, cNT, bsum, OFFS);
  fill3_kernel<<<NDIV_UP(cET, 256), 256, 0, stream>>>(src1, dst1, src2, dst2,
                                                      src3, dst3, flag, OFFS, EID);

  // Layer 1: mean(x) -> M1 ; h1 = gemm(M1, x fp32) -> M1 (bf16, in-place)
  gather_kernel<true><<<NDIV_UP(cN1, 4), 256, 0, stream>>>(
      x, OFFS, EID, 0, M1, cN1);
  gemm_kernel<true, false><<<NDIV_UP(cN1, 128), 256, 0, stream>>>(
      M1, x, wpk, b1, a1, M1, cN1);

  // Layer 2: mean(h1) -> M2 ; h2 = gemm(M2, h1 bf16) -> M2 (bf16, in-place)
  gather_kernel<false><<<NDIV_UP(cN2, 4), 256, 0, stream>>>(
      M1, OFFS, EID, cN1, M2, cN2);
  gemm_kernel<false, false><<<NDIV_UP(cN2, 128), 256, 0, stream>>>(
      M2, M1, wpk + 32768, b2, a2, M2, cN2);

  // Layer 3: mean(h2) -> M3 ; out = gemm(M3, h2 bf16) -> d_out (fp32)
  gather_kernel<false><<<NDIV_UP(cN3, 4), 256, 0, stream>>>(
      M2, OFFS, EID, cN1 + cN2, M3, cN3);
  gemm_kernel<false, true><<<NDIV_UP(cN3, 128), 256, 0, stream>>>(
      M3, M2, wpk + 65536, b3, a3, d_out, cN3);
}